// Round 2
// baseline (1797.187 us; speedup 1.0000x reference)
//
#include <hip/hip_runtime.h>

#define N_NODES 100000
#define N_EDGES 3200000
#define N_GRAPHS 256
#define HID 64

// bucketed CSR build: 128 dst-nodes per bucket
#define BUCKET_SHIFT 7
#define NODES_PER_BUCKET 128
#define NBUCK 782            // ceil(100000/128)
#define BCAP 5120            // mean 4093, sigma ~64 -> 5120 is >15 sigma

__global__ void k_zero_int(int* p, int n) {
    int i = blockIdx.x * blockDim.x + threadIdx.x;
    if (i < n) p[i] = 0;
}

// pass 1: partition edges into buckets by dst>>7, pack src | (dst&127)<<24
__global__ __launch_bounds__(256) void k_bucket(
        const int* __restrict__ src, const int* __restrict__ dst,
        int* __restrict__ bcnt, unsigned* __restrict__ pairs, int n) {
    int i = blockIdx.x * blockDim.x + threadIdx.x;
    if (i >= n) return;
    int s = src[i], d = dst[i];
    int b = d >> BUCKET_SHIFT;
    int pos = atomicAdd(&bcnt[b], 1);
    if (pos < BCAP)
        pairs[b * BCAP + pos] = (unsigned)s | ((unsigned)(d & (NODES_PER_BUCKET - 1)) << 24);
}

// exclusive scan over NBUCK bucket counts (single block, 1024 threads)
__global__ void k_scan_buckets(const int* __restrict__ bcnt, int* __restrict__ bscan,
                               int* __restrict__ rowp_last) {
    __shared__ int s[1024];
    int t = threadIdx.x;
    int v = (t < NBUCK) ? bcnt[t] : 0;
    s[t] = v;
    __syncthreads();
    for (int off = 1; off < 1024; off <<= 1) {
        int add = (t >= off) ? s[t - off] : 0;
        __syncthreads();
        s[t] += add;
        __syncthreads();
    }
    if (t < NBUCK) bscan[t] = s[t] - v;  // exclusive
    if (t == NBUCK - 1) rowp_last[0] = s[t];  // total edges -> rowp[N_NODES]
}

// pass 2: per-bucket LDS sort -> coalesced esrc write; also emits rowp + dinv
__global__ __launch_bounds__(256) void k_pass2(
        const unsigned* __restrict__ pairs, const int* __restrict__ bcnt,
        const int* __restrict__ bscan, int* __restrict__ esrc,
        int* __restrict__ rowp, float* __restrict__ dinv) {
    __shared__ int lcnt[NODES_PER_BUCKET];
    __shared__ int lscan[NODES_PER_BUCKET];
    __shared__ int lcur[NODES_PER_BUCKET];
    __shared__ int lout[BCAP];
    int b = blockIdx.x;
    int t = threadIdx.x;
    int nb = min(bcnt[b], BCAP);
    int base = bscan[b];
    const unsigned* bp = pairs + (size_t)b * BCAP;

    if (t < NODES_PER_BUCKET) lcnt[t] = 0;
    __syncthreads();
    for (int i = t; i < nb; i += 256) atomicAdd(&lcnt[bp[i] >> 24], 1);
    __syncthreads();
    // inclusive scan of 128 counts
    if (t < NODES_PER_BUCKET) lscan[t] = lcnt[t];
    __syncthreads();
    for (int off = 1; off < NODES_PER_BUCKET; off <<= 1) {
        int add = (t < NODES_PER_BUCKET && t >= off) ? lscan[t - off] : 0;
        __syncthreads();
        if (t < NODES_PER_BUCKET) lscan[t] += add;
        __syncthreads();
    }
    if (t < NODES_PER_BUCKET) lcur[t] = lscan[t] - lcnt[t];  // exclusive
    __syncthreads();
    // scatter into LDS
    for (int i = t; i < nb; i += 256) {
        unsigned u = bp[i];
        int d = u >> 24;
        int p = atomicAdd(&lcur[d], 1);
        lout[p] = (int)(u & 0x00FFFFFFu);
    }
    __syncthreads();
    // coalesced write to final CSR
    for (int i = t; i < nb; i += 256) esrc[base + i] = lout[i];
    // per-node rowp + dinv
    int node = b * NODES_PER_BUCKET + t;
    if (t < NODES_PER_BUCKET && node < N_NODES) {
        rowp[node] = base + lscan[t] - lcnt[t];
        dinv[node] = rsqrtf((float)lcnt[t] + 1.0f);  // in-degree + self-loop
    }
}

// ---------------- GCN layers ----------------

__global__ __launch_bounds__(256) void k_transform1(
        const float* __restrict__ x, const float* __restrict__ W,
        const float* __restrict__ dinv, float* __restrict__ B) {
    int wid = (blockIdx.x * 256 + threadIdx.x) >> 6;
    int lane = threadIdx.x & 63;
    if (wid >= N_NODES) return;
    const float* xr = x + wid * 8;
    float acc = 0.f;
#pragma unroll
    for (int k = 0; k < 8; ++k) acc += xr[k] * W[k * 64 + lane];
    B[wid * 64 + lane] = acc * dinv[wid];
}

__global__ __launch_bounds__(256) void k_transform64(
        const float* __restrict__ A, const float* __restrict__ W,
        const float* __restrict__ dinv, float* __restrict__ B) {
    __shared__ float Wl[64 * 64];
    for (int j = threadIdx.x; j < 64 * 64; j += 256) Wl[j] = W[j];
    __syncthreads();
    int wid = (blockIdx.x * 256 + threadIdx.x) >> 6;
    int lane = threadIdx.x & 63;
    if (wid >= N_NODES) return;
    const float* ar = A + wid * 64;
    float acc = 0.f;
#pragma unroll
    for (int k = 0; k < 64; ++k) acc += ar[k] * Wl[k * 64 + lane];
    B[wid * 64 + lane] = acc * dinv[wid];
}

template <int RELU>
__global__ __launch_bounds__(256) void k_aggregate(
        const float* __restrict__ B, float* __restrict__ A,
        const float* __restrict__ dinv, const int* __restrict__ rp,
        const int* __restrict__ esrc, const float* __restrict__ bias) {
    int wid = (blockIdx.x * 256 + threadIdx.x) >> 6;
    int lane = threadIdx.x & 63;
    if (wid >= N_NODES) return;
    int beg = rp[wid], end = rp[wid + 1];
    float acc = B[wid * 64 + lane];  // self loop
    for (int e0 = beg; e0 < end; e0 += 64) {
        int myE = e0 + lane;
        int s = (myE < end) ? esrc[myE] : 0;
        int c = min(64, end - e0);
        for (int j = 0; j < c; ++j) {
            int sj = __shfl(s, j);
            acc += B[sj * 64 + lane];
        }
    }
    float out = dinv[wid] * acc + bias[lane];
    A[wid * 64 + lane] = RELU ? fmaxf(out, 0.f) : out;
}

// ---------------- pooling + heads ----------------

__global__ void k_gstart(const int* __restrict__ batch, int* __restrict__ gstart) {
    int g = threadIdx.x;
    int lo = 0, hi = N_NODES;
    while (lo < hi) {
        int mid = (lo + hi) >> 1;
        if (batch[mid] < g) lo = mid + 1; else hi = mid;
    }
    gstart[g] = lo;
    if (g == 0) gstart[N_GRAPHS] = N_NODES;
}

__global__ __launch_bounds__(256) void k_pool(
        const float* __restrict__ A, const int* __restrict__ gstart,
        float* __restrict__ xgp) {
    int g = blockIdx.x;
    int beg = gstart[g], end = gstart[g + 1];
    int lane = threadIdx.x & 63, grp = threadIdx.x >> 6;
    float acc = 0.f;
    for (int r = beg + grp; r < end; r += 4) acc += A[r * 64 + lane];
    __shared__ float l[256];
    l[threadIdx.x] = acc;
    __syncthreads();
    if (threadIdx.x < 64) {
        float s = l[threadIdx.x] + l[threadIdx.x + 64] + l[threadIdx.x + 128] + l[threadIdx.x + 192];
        float c = (float)(end - beg);
        xgp[g * 64 + threadIdx.x] = s / fmaxf(c, 1.f);
    }
}

__global__ __launch_bounds__(256) void k_xglobal(
        const float* __restrict__ xgp, const float* __restrict__ Wg,
        const float* __restrict__ bg, float* __restrict__ xg) {
    int wid = (blockIdx.x * 256 + threadIdx.x) >> 6;
    int lane = threadIdx.x & 63;
    if (wid >= N_GRAPHS) return;
    float acc = bg[lane];
#pragma unroll 16
    for (int k = 0; k < 64; ++k) acc += xgp[wid * 64 + k] * Wg[k * 64 + lane];
    xg[wid * 64 + lane] = fmaxf(acc, 0.f);
}

__global__ void k_heuristic(const float* __restrict__ xg,
                            const float* __restrict__ Wh1, const float* __restrict__ bh1,
                            const float* __restrict__ Wh2, const float* __restrict__ bh2,
                            float* __restrict__ out) {
    int g = threadIdx.x;
    const float* r = xg + g * 64;
    float acc = bh2[0];
    for (int j = 0; j < 32; ++j) {
        float hj = bh1[j];
#pragma unroll 16
        for (int k = 0; k < 64; ++k) hj += r[k] * Wh1[k * 32 + j];
        acc += fmaxf(hj, 0.f) * Wh2[j];
    }
    out[g] = acc;
}

__global__ __launch_bounds__(256) void k_heads(
        const float* __restrict__ h,
        const float* __restrict__ Wm1, const float* __restrict__ bm1,
        const float* __restrict__ Wm2, const float* __restrict__ bm2,
        const float* __restrict__ Wp1, const float* __restrict__ bp1,
        const float* __restrict__ Wp2, const float* __restrict__ bp2,
        float* __restrict__ out_m, float* __restrict__ out_p) {
    int wid = (blockIdx.x * 256 + threadIdx.x) >> 6;
    int lane = threadIdx.x & 63;
    if (wid >= N_NODES) return;
    const float* hr = h + wid * 64;

    float m = bm1[lane];
#pragma unroll 16
    for (int k = 0; k < 64; ++k) m += hr[k] * Wm1[k * 64 + lane];
    m = fmaxf(m, 0.f);

#pragma unroll
    for (int j = 0; j < 9; ++j) {
        float p = m * Wm2[lane * 9 + j];
#pragma unroll
        for (int off = 32; off; off >>= 1) p += __shfl_xor(p, off);
        if (lane == j) out_m[wid * 9 + j] = p + bm2[j];
    }

    float pv = 0.f;
    if (lane < 32) {
        float p1 = bp1[lane];
#pragma unroll 16
        for (int k = 0; k < 64; ++k) p1 += hr[k] * Wp1[k * 32 + lane];
        pv = fmaxf(p1, 0.f) * Wp2[lane];
    }
#pragma unroll
    for (int off = 32; off; off >>= 1) pv += __shfl_xor(pv, off);
    if (lane == 0) out_p[wid] = pv + bp2[0];
}

// ---------------- launch ----------------

extern "C" void kernel_launch(void* const* d_in, const int* in_sizes, int n_in,
                              void* d_out, int out_size, void* d_ws, size_t ws_size,
                              hipStream_t stream) {
    const float* x    = (const float*)d_in[0];
    const int*   ei   = (const int*)d_in[1];
    const int*   batch= (const int*)d_in[2];
    const float* W1   = (const float*)d_in[3];
    const float* b1   = (const float*)d_in[4];
    const float* W2   = (const float*)d_in[5];
    const float* b2   = (const float*)d_in[6];
    const float* W3   = (const float*)d_in[7];
    const float* b3   = (const float*)d_in[8];
    const float* Wg   = (const float*)d_in[9];
    const float* bg   = (const float*)d_in[10];
    const float* Wh1  = (const float*)d_in[11];
    const float* bh1  = (const float*)d_in[12];
    const float* Wh2  = (const float*)d_in[13];
    const float* bh2  = (const float*)d_in[14];
    const float* Wm1  = (const float*)d_in[15];
    const float* bm1  = (const float*)d_in[16];
    const float* Wm2  = (const float*)d_in[17];
    const float* bm2  = (const float*)d_in[18];
    const float* Wp1  = (const float*)d_in[19];
    const float* bp1  = (const float*)d_in[20];
    const float* Wp2  = (const float*)d_in[21];
    const float* bp2  = (const float*)d_in[22];

    const int* e_src = ei;
    const int* e_dst = ei + N_EDGES;

    char* ws = (char*)d_ws;
    size_t off = 0;
    auto alloc = [&](size_t bytes) {
        void* p = ws + off;
        off += (bytes + 255) & ~(size_t)255;
        return p;
    };
    float* bufA   = (float*)alloc(N_NODES * 64 * sizeof(float));   // 25.6 MB
    float* bufB   = (float*)alloc(N_NODES * 64 * sizeof(float));   // 25.6 MB
    float* dinv   = (float*)alloc(N_NODES * sizeof(float));
    int*   rowp   = (int*)  alloc((N_NODES + 1) * sizeof(int));
    int*   esrc   = (int*)  alloc(N_EDGES * sizeof(int));          // 12.8 MB
    int*   bcnt   = (int*)  alloc(NBUCK * sizeof(int));
    int*   bscan  = (int*)  alloc(NBUCK * sizeof(int));
    int*   gstart = (int*)  alloc((N_GRAPHS + 1) * sizeof(int));
    float* xgp    = (float*)alloc(N_GRAPHS * 64 * sizeof(float));
    float* xg     = (float*)alloc(N_GRAPHS * 64 * sizeof(float));
    // bucket pair storage (16 MB) aliases bufA: only live before first transform
    unsigned* pairs = (unsigned*)bufA;
    (void)ws_size; (void)n_in; (void)in_sizes; (void)out_size;

    float* out_h = (float*)d_out;                // [256]
    float* out_m = (float*)d_out + 256;          // [100000*9]
    float* out_p = (float*)d_out + 256 + 900000; // [100000]

    const int TB = 256;
    dim3 blkE((N_EDGES + TB - 1) / TB);
    dim3 blkWave((N_NODES * 64 + TB - 1) / TB);  // one wave per node

    // CSR build (bucketed two-pass)
    k_zero_int<<<1, 1024, 0, stream>>>(bcnt, NBUCK);
    k_bucket<<<blkE, TB, 0, stream>>>(e_src, e_dst, bcnt, pairs, N_EDGES);
    k_scan_buckets<<<1, 1024, 0, stream>>>(bcnt, bscan, rowp + N_NODES);
    k_pass2<<<NBUCK, TB, 0, stream>>>(pairs, bcnt, bscan, esrc, rowp, dinv);

    // layer 1
    k_transform1<<<blkWave, TB, 0, stream>>>(x, W1, dinv, bufB);
    k_aggregate<1><<<blkWave, TB, 0, stream>>>(bufB, bufA, dinv, rowp, esrc, b1);
    // layer 2
    k_transform64<<<blkWave, TB, 0, stream>>>(bufA, W2, dinv, bufB);
    k_aggregate<1><<<blkWave, TB, 0, stream>>>(bufB, bufA, dinv, rowp, esrc, b2);
    // layer 3 (no relu)
    k_transform64<<<blkWave, TB, 0, stream>>>(bufA, W3, dinv, bufB);
    k_aggregate<0><<<blkWave, TB, 0, stream>>>(bufB, bufA, dinv, rowp, esrc, b3);

    // pooling + global head
    k_gstart<<<1, N_GRAPHS, 0, stream>>>(batch, gstart);
    k_pool<<<N_GRAPHS, TB, 0, stream>>>(bufA, gstart, xgp);
    k_xglobal<<<(N_GRAPHS * 64 + TB - 1) / TB, TB, 0, stream>>>(xgp, Wg, bg, xg);
    k_heuristic<<<1, N_GRAPHS, 0, stream>>>(xg, Wh1, bh1, Wh2, bh2, out_h);

    // node heads
    k_heads<<<blkWave, TB, 0, stream>>>(bufA, Wm1, bm1, Wm2, bm2,
                                        Wp1, bp1, Wp2, bp2, out_m, out_p);
}

// Round 4
// 1084.389 us; speedup vs baseline: 1.6573x; 1.6573x over previous
//
#include <hip/hip_runtime.h>

#define N_NODES 100000
#define N_EDGES 3200000
#define N_GRAPHS 256
#define HID 64

// atomic-free bucketed CSR build
#define BSHIFT 7                 // 128 nodes per bucket
#define NPB 128                  // nodes per bucket
#define NBUCK 782                // ceil(100000/128)
#define PCHUNK 8192              // edges per partition block
#define NPBLK 391                // ceil(3200000/8192)
#define SCAP 5120                // per-bucket sort capacity (mean 4093, sigma 64 -> +16 sigma)

// pass A: per-block private LDS histogram over buckets
__global__ __launch_bounds__(256) void k_hist(
        const int* __restrict__ dst, int* __restrict__ hist) {
    __shared__ int h[NBUCK];
    int t = threadIdx.x;
    for (int j = t; j < NBUCK; j += 256) h[j] = 0;
    __syncthreads();
    int base = blockIdx.x * PCHUNK;
    int end = min(base + PCHUNK, N_EDGES);
    for (int i = base + t; i < end; i += 256)
        atomicAdd(&h[dst[i] >> BSHIFT], 1);
    __syncthreads();
    for (int j = t; j < NBUCK; j += 256) hist[j * NPBLK + blockIdx.x] = h[j];
}

// pass B1: per-bucket exclusive scan over block counts (in place), emit totals
__global__ __launch_bounds__(512) void k_scan_rows(
        int* __restrict__ hist, int* __restrict__ btotal) {
    __shared__ int s[512];
    int b = blockIdx.x, t = threadIdx.x;
    int v = (t < NPBLK) ? hist[b * NPBLK + t] : 0;
    s[t] = v;
    __syncthreads();
    for (int off = 1; off < 512; off <<= 1) {
        int add = (t >= off) ? s[t - off] : 0;
        __syncthreads();
        s[t] += add;
        __syncthreads();
    }
    if (t < NPBLK) hist[b * NPBLK + t] = s[t] - v;  // exclusive within bucket
    if (t == 511) btotal[b] = s[511];
}

// pass B2: exclusive scan over NBUCK bucket totals (single block, 1024 threads)
__global__ __launch_bounds__(1024) void k_scan_base(
        const int* __restrict__ btotal, int* __restrict__ bbase,
        int* __restrict__ rowp_last) {
    __shared__ int s[1024];
    int t = threadIdx.x;
    int v = (t < NBUCK) ? btotal[t] : 0;
    s[t] = v;
    __syncthreads();
    for (int off = 1; off < 1024; off <<= 1) {
        int add = (t >= off) ? s[t - off] : 0;
        __syncthreads();
        s[t] += add;
        __syncthreads();
    }
    if (t < NBUCK) bbase[t] = s[t] - v;
    if (t == NBUCK - 1) rowp_last[0] = s[t];
}

// pass C: scatter packed pairs using exact per-(block,bucket) offsets (LDS cursors)
__global__ __launch_bounds__(256) void k_scatter(
        const int* __restrict__ src, const int* __restrict__ dst,
        const int* __restrict__ hist, const int* __restrict__ bbase,
        unsigned* __restrict__ pairs) {
    __shared__ int cur[NBUCK];
    int t = threadIdx.x;
    for (int j = t; j < NBUCK; j += 256)
        cur[j] = bbase[j] + hist[j * NPBLK + blockIdx.x];
    __syncthreads();
    int base = blockIdx.x * PCHUNK;
    int end = min(base + PCHUNK, N_EDGES);
    for (int i = base + t; i < end; i += 256) {
        int d = dst[i], s = src[i];
        int b = d >> BSHIFT;
        int pos = atomicAdd(&cur[b], 1);
        pairs[pos] = (unsigned)s | ((unsigned)(d & (NPB - 1)) << 24);
    }
}

// pass D: per-bucket LDS counting sort -> sorted esrc + rowp + dinv
__global__ __launch_bounds__(256) void k_sort(
        const unsigned* __restrict__ pairs, const int* __restrict__ btotal,
        const int* __restrict__ bbase, int* __restrict__ esrc,
        int* __restrict__ rowp, float* __restrict__ dinv) {
    __shared__ int lcnt[NPB];
    __shared__ int lscan[NPB];
    __shared__ int lcur[NPB];
    __shared__ int lout[SCAP];
    int b = blockIdx.x, t = threadIdx.x;
    int nb = min(btotal[b], SCAP);
    int base = bbase[b];
    if (t < NPB) lcnt[t] = 0;
    __syncthreads();
    for (int i = t; i < nb; i += 256) atomicAdd(&lcnt[pairs[base + i] >> 24], 1);
    __syncthreads();
    if (t < NPB) lscan[t] = lcnt[t];
    __syncthreads();
    for (int off = 1; off < NPB; off <<= 1) {
        int add = (t < NPB && t >= off) ? lscan[t - off] : 0;
        __syncthreads();
        if (t < NPB) lscan[t] += add;
        __syncthreads();
    }
    if (t < NPB) lcur[t] = lscan[t] - lcnt[t];
    __syncthreads();
    for (int i = t; i < nb; i += 256) {
        unsigned u = pairs[base + i];
        int p = atomicAdd(&lcur[u >> 24], 1);
        lout[p] = (int)(u & 0x00FFFFFFu);
    }
    __syncthreads();
    for (int i = t; i < nb; i += 256) esrc[base + i] = lout[i];
    int node = b * NPB + t;
    if (t < NPB && node < N_NODES) {
        rowp[node] = base + lscan[t] - lcnt[t];
        dinv[node] = rsqrtf((float)lcnt[t] + 1.0f);  // in-degree + self-loop
    }
}

// ---------------- GCN layers ----------------

__global__ __launch_bounds__(256) void k_transform1(
        const float* __restrict__ x, const float* __restrict__ W,
        const float* __restrict__ dinv, float* __restrict__ B) {
    int wid = (blockIdx.x * 256 + threadIdx.x) >> 6;
    int lane = threadIdx.x & 63;
    if (wid >= N_NODES) return;
    const float* xr = x + wid * 8;
    float acc = 0.f;
#pragma unroll
    for (int k = 0; k < 8; ++k) acc += xr[k] * W[k * 64 + lane];
    B[wid * 64 + lane] = acc * dinv[wid];
}

__global__ __launch_bounds__(256) void k_transform64(
        const float* __restrict__ A, const float* __restrict__ W,
        const float* __restrict__ dinv, float* __restrict__ B) {
    __shared__ float Wl[64 * 64];
    for (int j = threadIdx.x; j < 64 * 64; j += 256) Wl[j] = W[j];
    __syncthreads();
    int wid = (blockIdx.x * 256 + threadIdx.x) >> 6;
    int lane = threadIdx.x & 63;
    if (wid >= N_NODES) return;
    const float* ar = A + wid * 64;
    float acc = 0.f;
#pragma unroll
    for (int k = 0; k < 64; ++k) acc += ar[k] * Wl[k * 64 + lane];
    B[wid * 64 + lane] = acc * dinv[wid];
}

template <int RELU>
__global__ __launch_bounds__(256) void k_aggregate(
        const float* __restrict__ B, float* __restrict__ A,
        const float* __restrict__ dinv, const int* __restrict__ rp,
        const int* __restrict__ esrc, const float* __restrict__ bias) {
    int wid = (blockIdx.x * 256 + threadIdx.x) >> 6;
    int lane = threadIdx.x & 63;
    if (wid >= N_NODES) return;
    int beg = rp[wid], end = rp[wid + 1];
    float acc = B[wid * 64 + lane];  // self loop
    for (int e0 = beg; e0 < end; e0 += 64) {
        int myE = e0 + lane;
        int s = (myE < end) ? esrc[myE] : 0;
        int c = min(64, end - e0);
        for (int j = 0; j < c; ++j) {
            int sj = __shfl(s, j);
            acc += B[sj * 64 + lane];
        }
    }
    float out = dinv[wid] * acc + bias[lane];
    A[wid * 64 + lane] = RELU ? fmaxf(out, 0.f) : out;
}

// ---------------- pooling + heads ----------------

__global__ void k_gstart(const int* __restrict__ batch, int* __restrict__ gstart) {
    int g = threadIdx.x;
    int lo = 0, hi = N_NODES;
    while (lo < hi) {
        int mid = (lo + hi) >> 1;
        if (batch[mid] < g) lo = mid + 1; else hi = mid;
    }
    gstart[g] = lo;
    if (g == 0) gstart[N_GRAPHS] = N_NODES;
}

__global__ __launch_bounds__(256) void k_pool(
        const float* __restrict__ A, const int* __restrict__ gstart,
        float* __restrict__ xgp) {
    int g = blockIdx.x;
    int beg = gstart[g], end = gstart[g + 1];
    int lane = threadIdx.x & 63, grp = threadIdx.x >> 6;
    float acc = 0.f;
    for (int r = beg + grp; r < end; r += 4) acc += A[r * 64 + lane];
    __shared__ float l[256];
    l[threadIdx.x] = acc;
    __syncthreads();
    if (threadIdx.x < 64) {
        float s = l[threadIdx.x] + l[threadIdx.x + 64] + l[threadIdx.x + 128] + l[threadIdx.x + 192];
        float c = (float)(end - beg);
        xgp[g * 64 + threadIdx.x] = s / fmaxf(c, 1.f);
    }
}

__global__ __launch_bounds__(256) void k_xglobal(
        const float* __restrict__ xgp, const float* __restrict__ Wg,
        const float* __restrict__ bg, float* __restrict__ xg) {
    int wid = (blockIdx.x * 256 + threadIdx.x) >> 6;
    int lane = threadIdx.x & 63;
    if (wid >= N_GRAPHS) return;
    float acc = bg[lane];
#pragma unroll 16
    for (int k = 0; k < 64; ++k) acc += xgp[wid * 64 + k] * Wg[k * 64 + lane];
    xg[wid * 64 + lane] = fmaxf(acc, 0.f);
}

__global__ void k_heuristic(const float* __restrict__ xg,
                            const float* __restrict__ Wh1, const float* __restrict__ bh1,
                            const float* __restrict__ Wh2, const float* __restrict__ bh2,
                            float* __restrict__ out) {
    int g = threadIdx.x;
    const float* r = xg + g * 64;
    float acc = bh2[0];
    for (int j = 0; j < 32; ++j) {
        float hj = bh1[j];
#pragma unroll 16
        for (int k = 0; k < 64; ++k) hj += r[k] * Wh1[k * 32 + j];
        acc += fmaxf(hj, 0.f) * Wh2[j];
    }
    out[g] = acc;
}

__global__ __launch_bounds__(256) void k_heads(
        const float* __restrict__ h,
        const float* __restrict__ Wm1, const float* __restrict__ bm1,
        const float* __restrict__ Wm2, const float* __restrict__ bm2,
        const float* __restrict__ Wp1, const float* __restrict__ bp1,
        const float* __restrict__ Wp2, const float* __restrict__ bp2,
        float* __restrict__ out_m, float* __restrict__ out_p) {
    int wid = (blockIdx.x * 256 + threadIdx.x) >> 6;
    int lane = threadIdx.x & 63;
    if (wid >= N_NODES) return;
    const float* hr = h + wid * 64;

    float m = bm1[lane];
#pragma unroll 16
    for (int k = 0; k < 64; ++k) m += hr[k] * Wm1[k * 64 + lane];
    m = fmaxf(m, 0.f);

#pragma unroll
    for (int j = 0; j < 9; ++j) {
        float p = m * Wm2[lane * 9 + j];
#pragma unroll
        for (int off = 32; off; off >>= 1) p += __shfl_xor(p, off);
        if (lane == j) out_m[wid * 9 + j] = p + bm2[j];
    }

    float pv = 0.f;
    if (lane < 32) {
        float p1 = bp1[lane];
#pragma unroll 16
        for (int k = 0; k < 64; ++k) p1 += hr[k] * Wp1[k * 32 + lane];
        pv = fmaxf(p1, 0.f) * Wp2[lane];
    }
#pragma unroll
    for (int off = 32; off; off >>= 1) pv += __shfl_xor(pv, off);
    if (lane == 0) out_p[wid] = pv + bp2[0];
}

// ---------------- launch ----------------

extern "C" void kernel_launch(void* const* d_in, const int* in_sizes, int n_in,
                              void* d_out, int out_size, void* d_ws, size_t ws_size,
                              hipStream_t stream) {
    const float* x    = (const float*)d_in[0];
    const int*   ei   = (const int*)d_in[1];
    const int*   batch= (const int*)d_in[2];
    const float* W1   = (const float*)d_in[3];
    const float* b1   = (const float*)d_in[4];
    const float* W2   = (const float*)d_in[5];
    const float* b2   = (const float*)d_in[6];
    const float* W3   = (const float*)d_in[7];
    const float* b3   = (const float*)d_in[8];
    const float* Wg   = (const float*)d_in[9];
    const float* bg   = (const float*)d_in[10];
    const float* Wh1  = (const float*)d_in[11];
    const float* bh1  = (const float*)d_in[12];
    const float* Wh2  = (const float*)d_in[13];
    const float* bh2  = (const float*)d_in[14];
    const float* Wm1  = (const float*)d_in[15];
    const float* bm1  = (const float*)d_in[16];
    const float* Wm2  = (const float*)d_in[17];
    const float* bm2  = (const float*)d_in[18];
    const float* Wp1  = (const float*)d_in[19];
    const float* bp1  = (const float*)d_in[20];
    const float* Wp2  = (const float*)d_in[21];
    const float* bp2  = (const float*)d_in[22];

    const int* e_src = ei;
    const int* e_dst = ei + N_EDGES;

    char* ws = (char*)d_ws;
    size_t off = 0;
    auto alloc = [&](size_t bytes) {
        void* p = ws + off;
        off += (bytes + 255) & ~(size_t)255;
        return p;
    };
    float* bufA   = (float*)alloc(N_NODES * 64 * sizeof(float));   // 25.6 MB
    float* bufB   = (float*)alloc(N_NODES * 64 * sizeof(float));   // 25.6 MB
    float* dinv   = (float*)alloc(N_NODES * sizeof(float));
    int*   rowp   = (int*)  alloc((N_NODES + 1) * sizeof(int));
    int*   esrc   = (int*)  alloc(N_EDGES * sizeof(int));          // 12.8 MB
    int*   hist   = (int*)  alloc((size_t)NBUCK * NPBLK * sizeof(int)); // 1.22 MB
    int*   btotal = (int*)  alloc(NBUCK * sizeof(int));
    int*   bbase  = (int*)  alloc(NBUCK * sizeof(int));
    int*   gstart = (int*)  alloc((N_GRAPHS + 1) * sizeof(int));
    float* xgp    = (float*)alloc(N_GRAPHS * 64 * sizeof(float));
    float* xg     = (float*)alloc(N_GRAPHS * 64 * sizeof(float));
    // packed pairs (12.8 MB) alias bufA: only live before the first transform
    unsigned* pairs = (unsigned*)bufA;
    (void)ws_size; (void)n_in; (void)in_sizes; (void)out_size;

    float* out_h = (float*)d_out;                // [256]
    float* out_m = (float*)d_out + 256;          // [100000*9]
    float* out_p = (float*)d_out + 256 + 900000; // [100000]

    const int TB = 256;
    dim3 blkWave((N_NODES * 64 + TB - 1) / TB);  // one wave per node

    // CSR build — atomic-free 3-pass partition + per-bucket LDS sort
    k_hist<<<NPBLK, TB, 0, stream>>>(e_dst, hist);
    k_scan_rows<<<NBUCK, 512, 0, stream>>>(hist, btotal);
    k_scan_base<<<1, 1024, 0, stream>>>(btotal, bbase, rowp + N_NODES);
    k_scatter<<<NPBLK, TB, 0, stream>>>(e_src, e_dst, hist, bbase, pairs);
    k_sort<<<NBUCK, TB, 0, stream>>>(pairs, btotal, bbase, esrc, rowp, dinv);

    // layer 1
    k_transform1<<<blkWave, TB, 0, stream>>>(x, W1, dinv, bufB);
    k_aggregate<1><<<blkWave, TB, 0, stream>>>(bufB, bufA, dinv, rowp, esrc, b1);
    // layer 2
    k_transform64<<<blkWave, TB, 0, stream>>>(bufA, W2, dinv, bufB);
    k_aggregate<1><<<blkWave, TB, 0, stream>>>(bufB, bufA, dinv, rowp, esrc, b2);
    // layer 3 (no relu)
    k_transform64<<<blkWave, TB, 0, stream>>>(bufA, W3, dinv, bufB);
    k_aggregate<0><<<blkWave, TB, 0, stream>>>(bufB, bufA, dinv, rowp, esrc, b3);

    // pooling + global head
    k_gstart<<<1, N_GRAPHS, 0, stream>>>(batch, gstart);
    k_pool<<<N_GRAPHS, TB, 0, stream>>>(bufA, gstart, xgp);
    k_xglobal<<<(N_GRAPHS * 64 + TB - 1) / TB, TB, 0, stream>>>(xgp, Wg, bg, xg);
    k_heuristic<<<1, N_GRAPHS, 0, stream>>>(xg, Wh1, bh1, Wh2, bh2, out_h);

    // node heads
    k_heads<<<blkWave, TB, 0, stream>>>(bufA, Wm1, bm1, Wm2, bm2,
                                        Wp1, bp1, Wp2, bp2, out_m, out_p);
}

// Round 5
// 979.594 us; speedup vs baseline: 1.8346x; 1.1070x over previous
//
#include <hip/hip_runtime.h>

#define N_NODES 100000
#define N_EDGES 3200000
#define N_GRAPHS 256
#define HID 64

// atomic-free bucketed CSR build
#define BSHIFT 7                 // 128 nodes per bucket
#define NPB 128                  // nodes per bucket
#define NBUCK 782                // ceil(100000/128)
#define PCHUNK 8192              // edges per partition block
#define NPBLK 391                // ceil(3200000/8192)
#define SCAP 5120                // per-bucket sort capacity (mean 4093, sigma 64 -> +16 sigma)

// pass A: per-block private LDS histogram over buckets
__global__ __launch_bounds__(256) void k_hist(
        const int* __restrict__ dst, int* __restrict__ hist) {
    __shared__ int h[NBUCK];
    int t = threadIdx.x;
    for (int j = t; j < NBUCK; j += 256) h[j] = 0;
    __syncthreads();
    int base = blockIdx.x * PCHUNK;
    int end = min(base + PCHUNK, N_EDGES);
    for (int i = base + t; i < end; i += 256)
        atomicAdd(&h[dst[i] >> BSHIFT], 1);
    __syncthreads();
    for (int j = t; j < NBUCK; j += 256) hist[j * NPBLK + blockIdx.x] = h[j];
}

// pass B1: per-bucket exclusive scan over block counts (in place), emit totals
__global__ __launch_bounds__(512) void k_scan_rows(
        int* __restrict__ hist, int* __restrict__ btotal) {
    __shared__ int s[512];
    int b = blockIdx.x, t = threadIdx.x;
    int v = (t < NPBLK) ? hist[b * NPBLK + t] : 0;
    s[t] = v;
    __syncthreads();
    for (int off = 1; off < 512; off <<= 1) {
        int add = (t >= off) ? s[t - off] : 0;
        __syncthreads();
        s[t] += add;
        __syncthreads();
    }
    if (t < NPBLK) hist[b * NPBLK + t] = s[t] - v;  // exclusive within bucket
    if (t == 511) btotal[b] = s[511];
}

// pass B2: exclusive scan over NBUCK bucket totals (single block, 1024 threads)
__global__ __launch_bounds__(1024) void k_scan_base(
        const int* __restrict__ btotal, int* __restrict__ bbase,
        int* __restrict__ rowp_last) {
    __shared__ int s[1024];
    int t = threadIdx.x;
    int v = (t < NBUCK) ? btotal[t] : 0;
    s[t] = v;
    __syncthreads();
    for (int off = 1; off < 1024; off <<= 1) {
        int add = (t >= off) ? s[t - off] : 0;
        __syncthreads();
        s[t] += add;
        __syncthreads();
    }
    if (t < NBUCK) bbase[t] = s[t] - v;
    if (t == NBUCK - 1) rowp_last[0] = s[t];
}

// pass C: scatter packed pairs using exact per-(block,bucket) offsets (LDS cursors)
__global__ __launch_bounds__(256) void k_scatter(
        const int* __restrict__ src, const int* __restrict__ dst,
        const int* __restrict__ hist, const int* __restrict__ bbase,
        unsigned* __restrict__ pairs) {
    __shared__ int cur[NBUCK];
    int t = threadIdx.x;
    for (int j = t; j < NBUCK; j += 256)
        cur[j] = bbase[j] + hist[j * NPBLK + blockIdx.x];
    __syncthreads();
    int base = blockIdx.x * PCHUNK;
    int end = min(base + PCHUNK, N_EDGES);
    for (int i = base + t; i < end; i += 256) {
        int d = dst[i], s = src[i];
        int b = d >> BSHIFT;
        int pos = atomicAdd(&cur[b], 1);
        pairs[pos] = (unsigned)s | ((unsigned)(d & (NPB - 1)) << 24);
    }
}

// pass D: per-bucket LDS counting sort -> sorted esrc + rowp + dinv
__global__ __launch_bounds__(256) void k_sort(
        const unsigned* __restrict__ pairs, const int* __restrict__ btotal,
        const int* __restrict__ bbase, int* __restrict__ esrc,
        int* __restrict__ rowp, float* __restrict__ dinv) {
    __shared__ int lcnt[NPB];
    __shared__ int lscan[NPB];
    __shared__ int lcur[NPB];
    __shared__ int lout[SCAP];
    int b = blockIdx.x, t = threadIdx.x;
    int nb = min(btotal[b], SCAP);
    int base = bbase[b];
    if (t < NPB) lcnt[t] = 0;
    __syncthreads();
    for (int i = t; i < nb; i += 256) atomicAdd(&lcnt[pairs[base + i] >> 24], 1);
    __syncthreads();
    if (t < NPB) lscan[t] = lcnt[t];
    __syncthreads();
    for (int off = 1; off < NPB; off <<= 1) {
        int add = (t < NPB && t >= off) ? lscan[t - off] : 0;
        __syncthreads();
        if (t < NPB) lscan[t] += add;
        __syncthreads();
    }
    if (t < NPB) lcur[t] = lscan[t] - lcnt[t];
    __syncthreads();
    for (int i = t; i < nb; i += 256) {
        unsigned u = pairs[base + i];
        int p = atomicAdd(&lcur[u >> 24], 1);
        lout[p] = (int)(u & 0x00FFFFFFu);
    }
    __syncthreads();
    for (int i = t; i < nb; i += 256) esrc[base + i] = lout[i];
    int node = b * NPB + t;
    if (t < NPB && node < N_NODES) {
        rowp[node] = base + lscan[t] - lcnt[t];
        dinv[node] = rsqrtf((float)lcnt[t] + 1.0f);  // in-degree + self-loop
    }
}

// ---------------- GCN layers ----------------

__global__ __launch_bounds__(256) void k_transform1(
        const float* __restrict__ x, const float* __restrict__ W,
        const float* __restrict__ dinv, float* __restrict__ B) {
    int wid = (blockIdx.x * 256 + threadIdx.x) >> 6;
    int lane = threadIdx.x & 63;
    if (wid >= N_NODES) return;
    const float* xr = x + wid * 8;
    float acc = 0.f;
#pragma unroll
    for (int k = 0; k < 8; ++k) acc += xr[k] * W[k * 64 + lane];
    B[wid * 64 + lane] = acc * dinv[wid];
}

__global__ __launch_bounds__(256) void k_transform64(
        const float* __restrict__ A, const float* __restrict__ W,
        const float* __restrict__ dinv, float* __restrict__ B) {
    __shared__ float Wl[64 * 64];
    for (int j = threadIdx.x; j < 64 * 64; j += 256) Wl[j] = W[j];
    __syncthreads();
    int wid = (blockIdx.x * 256 + threadIdx.x) >> 6;
    int lane = threadIdx.x & 63;
    if (wid >= N_NODES) return;
    const float* ar = A + wid * 64;
    float acc = 0.f;
#pragma unroll
    for (int k = 0; k < 64; ++k) acc += ar[k] * Wl[k * 64 + lane];
    B[wid * 64 + lane] = acc * dinv[wid];
}

template <int RELU>
__global__ __launch_bounds__(256) void k_aggregate(
        const float* __restrict__ B, float* __restrict__ A,
        const float* __restrict__ dinv, const int* __restrict__ rp,
        const int* __restrict__ esrc, const float* __restrict__ bias) {
    int wid = (blockIdx.x * 256 + threadIdx.x) >> 6;
    int lane = threadIdx.x & 63;
    if (wid >= N_NODES) return;
    int beg = rp[wid], end = rp[wid + 1];
    float acc = B[wid * 64 + lane];  // self loop
    for (int e0 = beg; e0 < end; e0 += 64) {
        int myE = e0 + lane;
        int s = (myE < end) ? esrc[myE] : 0;
        int c = min(64, end - e0);
        for (int j = 0; j < c; ++j) {
            int sj = __shfl(s, j);
            acc += B[sj * 64 + lane];
        }
    }
    float out = dinv[wid] * acc + bias[lane];
    A[wid * 64 + lane] = RELU ? fmaxf(out, 0.f) : out;
}

// ---------------- pooling + heads ----------------

__global__ void k_gstart(const int* __restrict__ batch, int* __restrict__ gstart) {
    int g = threadIdx.x;
    int lo = 0, hi = N_NODES;
    while (lo < hi) {
        int mid = (lo + hi) >> 1;
        if (batch[mid] < g) lo = mid + 1; else hi = mid;
    }
    gstart[g] = lo;
    if (g == 0) gstart[N_GRAPHS] = N_NODES;
}

__global__ __launch_bounds__(256) void k_pool(
        const float* __restrict__ A, const int* __restrict__ gstart,
        float* __restrict__ xgp) {
    int g = blockIdx.x;
    int beg = gstart[g], end = gstart[g + 1];
    int lane = threadIdx.x & 63, grp = threadIdx.x >> 6;
    float acc = 0.f;
    for (int r = beg + grp; r < end; r += 4) acc += A[r * 64 + lane];
    __shared__ float l[256];
    l[threadIdx.x] = acc;
    __syncthreads();
    if (threadIdx.x < 64) {
        float s = l[threadIdx.x] + l[threadIdx.x + 64] + l[threadIdx.x + 128] + l[threadIdx.x + 192];
        float c = (float)(end - beg);
        xgp[g * 64 + threadIdx.x] = s / fmaxf(c, 1.f);
    }
}

__global__ __launch_bounds__(256) void k_xglobal(
        const float* __restrict__ xgp, const float* __restrict__ Wg,
        const float* __restrict__ bg, float* __restrict__ xg) {
    int wid = (blockIdx.x * 256 + threadIdx.x) >> 6;
    int lane = threadIdx.x & 63;
    if (wid >= N_GRAPHS) return;
    float acc = bg[lane];
#pragma unroll 16
    for (int k = 0; k < 64; ++k) acc += xgp[wid * 64 + k] * Wg[k * 64 + lane];
    xg[wid * 64 + lane] = fmaxf(acc, 0.f);
}

__global__ void k_heuristic(const float* __restrict__ xg,
                            const float* __restrict__ Wh1, const float* __restrict__ bh1,
                            const float* __restrict__ Wh2, const float* __restrict__ bh2,
                            float* __restrict__ out) {
    int g = threadIdx.x;
    const float* r = xg + g * 64;
    float acc = bh2[0];
    for (int j = 0; j < 32; ++j) {
        float hj = bh1[j];
#pragma unroll 16
        for (int k = 0; k < 64; ++k) hj += r[k] * Wh1[k * 32 + j];
        acc += fmaxf(hj, 0.f) * Wh2[j];
    }
    out[g] = acc;
}

// node heads, stage 1: M = relu(h@Wm1+bm1) -> global; priority head fully in-register
__global__ __launch_bounds__(256) void k_mlp1(
        const float* __restrict__ h,
        const float* __restrict__ Wm1, const float* __restrict__ bm1,
        const float* __restrict__ Wp1, const float* __restrict__ bp1,
        const float* __restrict__ Wp2, const float* __restrict__ bp2,
        float* __restrict__ M, float* __restrict__ out_p) {
    __shared__ float Wm[64 * 64];   // [k][f]
    __shared__ float Wp[64 * 32];   // [k][j]
    for (int i = threadIdx.x; i < 64 * 64; i += 256) Wm[i] = Wm1[i];
    for (int i = threadIdx.x; i < 64 * 32; i += 256) Wp[i] = Wp1[i];
    __syncthreads();
    int wid = (blockIdx.x * 256 + threadIdx.x) >> 6;
    int lane = threadIdx.x & 63;
    if (wid >= N_NODES) return;
    const float* hr = h + wid * 64;

    // m[lane] = h . Wm1[:,lane]
    float m = bm1[lane];
#pragma unroll 16
    for (int k = 0; k < 64; ++k) m += hr[k] * Wm[k * 64 + lane];
    M[wid * 64 + lane] = fmaxf(m, 0.f);

    // p1[j] split-k: lanes (j, j+32) each sum one k-half
    int j = lane & 31;
    int kbase = (lane >> 5) * 32;
    float p = 0.f;
#pragma unroll 16
    for (int kk = 0; kk < 32; ++kk) {
        int k = kbase + kk;
        p += hr[k] * Wp[k * 32 + j];
    }
    p += __shfl_xor(p, 32);  // combine halves: lanes j and j+32 now both hold p1[j]
    float q = fmaxf(p + bp1[j], 0.f) * Wp2[j];
#pragma unroll
    for (int off = 16; off; off >>= 1) q += __shfl_xor(q, off);  // sum 32 j's
    if (lane == 0) out_p[wid] = q + bp2[0];
}

// node heads, stage 2: out_m[n][j] = M[n] . Wm2[:,j] + bm2[j] (thread per output)
__global__ __launch_bounds__(256) void k_mlp2(
        const float* __restrict__ M,
        const float* __restrict__ Wm2, const float* __restrict__ bm2,
        float* __restrict__ out_m) {
    __shared__ float W[64 * 9];
    __shared__ float bb[9];
    for (int i = threadIdx.x; i < 64 * 9; i += 256) W[i] = Wm2[i];
    if (threadIdx.x < 9) bb[threadIdx.x] = bm2[threadIdx.x];
    __syncthreads();
    int tid = blockIdx.x * 256 + threadIdx.x;
    if (tid >= N_NODES * 9) return;
    int n = tid / 9;
    int j = tid - n * 9;
    const float* Mr = M + n * 64;
    float acc = bb[j];
#pragma unroll 16
    for (int k = 0; k < 64; ++k) acc += Mr[k] * W[k * 9 + j];
    out_m[tid] = acc;
}

// ---------------- launch ----------------

extern "C" void kernel_launch(void* const* d_in, const int* in_sizes, int n_in,
                              void* d_out, int out_size, void* d_ws, size_t ws_size,
                              hipStream_t stream) {
    const float* x    = (const float*)d_in[0];
    const int*   ei   = (const int*)d_in[1];
    const int*   batch= (const int*)d_in[2];
    const float* W1   = (const float*)d_in[3];
    const float* b1   = (const float*)d_in[4];
    const float* W2   = (const float*)d_in[5];
    const float* b2   = (const float*)d_in[6];
    const float* W3   = (const float*)d_in[7];
    const float* b3   = (const float*)d_in[8];
    const float* Wg   = (const float*)d_in[9];
    const float* bg   = (const float*)d_in[10];
    const float* Wh1  = (const float*)d_in[11];
    const float* bh1  = (const float*)d_in[12];
    const float* Wh2  = (const float*)d_in[13];
    const float* bh2  = (const float*)d_in[14];
    const float* Wm1  = (const float*)d_in[15];
    const float* bm1  = (const float*)d_in[16];
    const float* Wm2  = (const float*)d_in[17];
    const float* bm2  = (const float*)d_in[18];
    const float* Wp1  = (const float*)d_in[19];
    const float* bp1  = (const float*)d_in[20];
    const float* Wp2  = (const float*)d_in[21];
    const float* bp2  = (const float*)d_in[22];

    const int* e_src = ei;
    const int* e_dst = ei + N_EDGES;

    char* ws = (char*)d_ws;
    size_t off = 0;
    auto alloc = [&](size_t bytes) {
        void* p = ws + off;
        off += (bytes + 255) & ~(size_t)255;
        return p;
    };
    float* bufA   = (float*)alloc(N_NODES * 64 * sizeof(float));   // 25.6 MB
    float* bufB   = (float*)alloc(N_NODES * 64 * sizeof(float));   // 25.6 MB
    float* dinv   = (float*)alloc(N_NODES * sizeof(float));
    int*   rowp   = (int*)  alloc((N_NODES + 1) * sizeof(int));
    int*   esrc   = (int*)  alloc(N_EDGES * sizeof(int));          // 12.8 MB
    int*   hist   = (int*)  alloc((size_t)NBUCK * NPBLK * sizeof(int)); // 1.22 MB
    int*   btotal = (int*)  alloc(NBUCK * sizeof(int));
    int*   bbase  = (int*)  alloc(NBUCK * sizeof(int));
    int*   gstart = (int*)  alloc((N_GRAPHS + 1) * sizeof(int));
    float* xgp    = (float*)alloc(N_GRAPHS * 64 * sizeof(float));
    float* xg     = (float*)alloc(N_GRAPHS * 64 * sizeof(float));
    // packed pairs (12.8 MB) alias bufA: only live before the first transform
    unsigned* pairs = (unsigned*)bufA;
    // M (hidden of move head) reuses bufB: free after the last transform+aggregate
    float* M = bufB;
    (void)ws_size; (void)n_in; (void)in_sizes; (void)out_size;

    float* out_h = (float*)d_out;                // [256]
    float* out_m = (float*)d_out + 256;          // [100000*9]
    float* out_p = (float*)d_out + 256 + 900000; // [100000]

    const int TB = 256;
    dim3 blkWave((N_NODES * 64 + TB - 1) / TB);  // one wave per node

    // CSR build — atomic-free 3-pass partition + per-bucket LDS sort
    k_hist<<<NPBLK, TB, 0, stream>>>(e_dst, hist);
    k_scan_rows<<<NBUCK, 512, 0, stream>>>(hist, btotal);
    k_scan_base<<<1, 1024, 0, stream>>>(btotal, bbase, rowp + N_NODES);
    k_scatter<<<NPBLK, TB, 0, stream>>>(e_src, e_dst, hist, bbase, pairs);
    k_sort<<<NBUCK, TB, 0, stream>>>(pairs, btotal, bbase, esrc, rowp, dinv);

    // layer 1
    k_transform1<<<blkWave, TB, 0, stream>>>(x, W1, dinv, bufB);
    k_aggregate<1><<<blkWave, TB, 0, stream>>>(bufB, bufA, dinv, rowp, esrc, b1);
    // layer 2
    k_transform64<<<blkWave, TB, 0, stream>>>(bufA, W2, dinv, bufB);
    k_aggregate<1><<<blkWave, TB, 0, stream>>>(bufB, bufA, dinv, rowp, esrc, b2);
    // layer 3 (no relu)
    k_transform64<<<blkWave, TB, 0, stream>>>(bufA, W3, dinv, bufB);
    k_aggregate<0><<<blkWave, TB, 0, stream>>>(bufB, bufA, dinv, rowp, esrc, b3);

    // pooling + global head
    k_gstart<<<1, N_GRAPHS, 0, stream>>>(batch, gstart);
    k_pool<<<N_GRAPHS, TB, 0, stream>>>(bufA, gstart, xgp);
    k_xglobal<<<(N_GRAPHS * 64 + TB - 1) / TB, TB, 0, stream>>>(xgp, Wg, bg, xg);
    k_heuristic<<<1, N_GRAPHS, 0, stream>>>(xg, Wh1, bh1, Wh2, bh2, out_h);

    // node heads (two-stage, reduce-free)
    k_mlp1<<<blkWave, TB, 0, stream>>>(bufA, Wm1, bm1, Wp1, bp1, Wp2, bp2, M, out_p);
    k_mlp2<<<(N_NODES * 9 + TB - 1) / TB, TB, 0, stream>>>(M, Wm2, bm2, out_m);
}

// Round 6
// 694.463 us; speedup vs baseline: 2.5879x; 1.4106x over previous
//
#include <hip/hip_runtime.h>

#define N_NODES 100000
#define N_EDGES 3200000
#define N_GRAPHS 256
#define HID 64

// atomic-free bucketed CSR build
#define BSHIFT 7                 // 128 nodes per bucket
#define NPB 128                  // nodes per bucket
#define NBUCK 782                // ceil(100000/128)
#define PCHUNK 8192              // edges per partition block
#define NPBLK 391                // ceil(3200000/8192)
#define SCAP 5120                // per-bucket sort capacity (mean 4093, sigma 64 -> +16 sigma)

// pass A: per-block private LDS histogram over buckets
__global__ __launch_bounds__(256) void k_hist(
        const int* __restrict__ dst, int* __restrict__ hist) {
    __shared__ int h[NBUCK];
    int t = threadIdx.x;
    for (int j = t; j < NBUCK; j += 256) h[j] = 0;
    __syncthreads();
    int base = blockIdx.x * PCHUNK;
    int end = min(base + PCHUNK, N_EDGES);
    for (int i = base + t; i < end; i += 256)
        atomicAdd(&h[dst[i] >> BSHIFT], 1);
    __syncthreads();
    for (int j = t; j < NBUCK; j += 256) hist[j * NPBLK + blockIdx.x] = h[j];
}

// pass B1: per-bucket exclusive scan over block counts (in place), emit totals
__global__ __launch_bounds__(512) void k_scan_rows(
        int* __restrict__ hist, int* __restrict__ btotal) {
    __shared__ int s[512];
    int b = blockIdx.x, t = threadIdx.x;
    int v = (t < NPBLK) ? hist[b * NPBLK + t] : 0;
    s[t] = v;
    __syncthreads();
    for (int off = 1; off < 512; off <<= 1) {
        int add = (t >= off) ? s[t - off] : 0;
        __syncthreads();
        s[t] += add;
        __syncthreads();
    }
    if (t < NPBLK) hist[b * NPBLK + t] = s[t] - v;  // exclusive within bucket
    if (t == 511) btotal[b] = s[511];
}

// pass B2: exclusive scan over NBUCK bucket totals (single block, 1024 threads)
__global__ __launch_bounds__(1024) void k_scan_base(
        const int* __restrict__ btotal, int* __restrict__ bbase,
        int* __restrict__ rowp_last) {
    __shared__ int s[1024];
    int t = threadIdx.x;
    int v = (t < NBUCK) ? btotal[t] : 0;
    s[t] = v;
    __syncthreads();
    for (int off = 1; off < 1024; off <<= 1) {
        int add = (t >= off) ? s[t - off] : 0;
        __syncthreads();
        s[t] += add;
        __syncthreads();
    }
    if (t < NBUCK) bbase[t] = s[t] - v;
    if (t == NBUCK - 1) rowp_last[0] = s[t];
}

// pass C: scatter packed pairs using exact per-(block,bucket) offsets (LDS cursors)
__global__ __launch_bounds__(256) void k_scatter(
        const int* __restrict__ src, const int* __restrict__ dst,
        const int* __restrict__ hist, const int* __restrict__ bbase,
        unsigned* __restrict__ pairs) {
    __shared__ int cur[NBUCK];
    int t = threadIdx.x;
    for (int j = t; j < NBUCK; j += 256)
        cur[j] = bbase[j] + hist[j * NPBLK + blockIdx.x];
    __syncthreads();
    int base = blockIdx.x * PCHUNK;
    int end = min(base + PCHUNK, N_EDGES);
    for (int i = base + t; i < end; i += 256) {
        int d = dst[i], s = src[i];
        int b = d >> BSHIFT;
        int pos = atomicAdd(&cur[b], 1);
        pairs[pos] = (unsigned)s | ((unsigned)(d & (NPB - 1)) << 24);
    }
}

// pass D: per-bucket LDS counting sort -> sorted esrc + rowp + dinv
__global__ __launch_bounds__(256) void k_sort(
        const unsigned* __restrict__ pairs, const int* __restrict__ btotal,
        const int* __restrict__ bbase, int* __restrict__ esrc,
        int* __restrict__ rowp, float* __restrict__ dinv) {
    __shared__ int lcnt[NPB];
    __shared__ int lscan[NPB];
    __shared__ int lcur[NPB];
    __shared__ int lout[SCAP];
    int b = blockIdx.x, t = threadIdx.x;
    int nb = min(btotal[b], SCAP);
    int base = bbase[b];
    if (t < NPB) lcnt[t] = 0;
    __syncthreads();
    for (int i = t; i < nb; i += 256) atomicAdd(&lcnt[pairs[base + i] >> 24], 1);
    __syncthreads();
    if (t < NPB) lscan[t] = lcnt[t];
    __syncthreads();
    for (int off = 1; off < NPB; off <<= 1) {
        int add = (t < NPB && t >= off) ? lscan[t - off] : 0;
        __syncthreads();
        if (t < NPB) lscan[t] += add;
        __syncthreads();
    }
    if (t < NPB) lcur[t] = lscan[t] - lcnt[t];
    __syncthreads();
    for (int i = t; i < nb; i += 256) {
        unsigned u = pairs[base + i];
        int p = atomicAdd(&lcur[u >> 24], 1);
        lout[p] = (int)(u & 0x00FFFFFFu);
    }
    __syncthreads();
    for (int i = t; i < nb; i += 256) esrc[base + i] = lout[i];
    int node = b * NPB + t;
    if (t < NPB && node < N_NODES) {
        rowp[node] = base + lscan[t] - lcnt[t];
        dinv[node] = rsqrtf((float)lcnt[t] + 1.0f);  // in-degree + self-loop
    }
}

// ---------------- GCN layers ----------------
// Re-associated pipeline:  xs = x*dinv;  y1 = agg(xs);  B2 = relu(y1@W1+b1)*dinv;
// y2 = agg(B2);  B3 = relu(y2@W2+b2)*dinv;  y3 = agg(B3);  h = y3@W3+b3.
// agg(B)[i] = dinv[i] * (B[i] + sum_{e: dst=i} B[src[e]])

// prescale x (8 features) by dinv
__global__ __launch_bounds__(256) void k_prescale(
        const float* __restrict__ x, const float* __restrict__ dinv,
        float* __restrict__ xs) {
    int tid = blockIdx.x * 256 + threadIdx.x;
    if (tid >= N_NODES * 8) return;
    xs[tid] = x[tid] * dinv[tid >> 3];
}

// 8-feature aggregate: lane-per-edge, float4x2 row loads, butterfly reduce.
__global__ __launch_bounds__(256) void k_agg8(
        const float* __restrict__ xs, float* __restrict__ Y,
        const float* __restrict__ dinv, const int* __restrict__ rp,
        const int* __restrict__ esrc) {
    int wid = (blockIdx.x * 256 + threadIdx.x) >> 6;
    int lane = threadIdx.x & 63;
    if (wid >= N_NODES) return;
    int beg = rp[wid], end = rp[wid + 1];
    float4 lo = {0.f, 0.f, 0.f, 0.f}, hi = {0.f, 0.f, 0.f, 0.f};
    for (int e = beg + lane; e < end; e += 64) {
        int s = esrc[e];
        const float4* r = (const float4*)(xs + (size_t)s * 8);
        float4 a = r[0], b = r[1];
        lo.x += a.x; lo.y += a.y; lo.z += a.z; lo.w += a.w;
        hi.x += b.x; hi.y += b.y; hi.z += b.z; hi.w += b.w;
    }
#pragma unroll
    for (int off = 32; off; off >>= 1) {
        lo.x += __shfl_xor(lo.x, off); lo.y += __shfl_xor(lo.y, off);
        lo.z += __shfl_xor(lo.z, off); lo.w += __shfl_xor(lo.w, off);
        hi.x += __shfl_xor(hi.x, off); hi.y += __shfl_xor(hi.y, off);
        hi.z += __shfl_xor(hi.z, off); hi.w += __shfl_xor(hi.w, off);
    }
    if (lane == 0) {
        const float4* r = (const float4*)(xs + (size_t)wid * 8);
        float4 a = r[0], b = r[1];
        float dv = dinv[wid];
        float* yo = Y + (size_t)wid * 8;
        yo[0] = dv * (lo.x + a.x); yo[1] = dv * (lo.y + a.y);
        yo[2] = dv * (lo.z + a.z); yo[3] = dv * (lo.w + a.w);
        yo[4] = dv * (hi.x + b.x); yo[5] = dv * (hi.y + b.y);
        yo[6] = dv * (hi.z + b.z); yo[7] = dv * (hi.w + b.w);
    }
}

// 64-feature aggregate: 8-wide MLP batches, clamped-index tail with masked adds
__global__ __launch_bounds__(256) void k_agg64(
        const float* __restrict__ B, float* __restrict__ Y,
        const float* __restrict__ dinv, const int* __restrict__ rp,
        const int* __restrict__ esrc) {
    int wid = (blockIdx.x * 256 + threadIdx.x) >> 6;
    int lane = threadIdx.x & 63;
    if (wid >= N_NODES) return;
    int beg = rp[wid], end = rp[wid + 1];
    float a0 = B[(size_t)wid * 64 + lane];  // self loop
    float a1 = 0.f, a2 = 0.f, a3 = 0.f, a4 = 0.f, a5 = 0.f, a6 = 0.f, a7 = 0.f;
    for (int e0 = beg; e0 < end; e0 += 64) {
        int myE = e0 + lane;
        int s = (myE < end) ? esrc[myE] : 0;
        int c = min(64, end - e0);
        int jm = c - 1;
        for (int j = 0; j < c; j += 8) {
            int s0 = __shfl(s, j);
            int s1 = __shfl(s, min(j + 1, jm));
            int s2 = __shfl(s, min(j + 2, jm));
            int s3 = __shfl(s, min(j + 3, jm));
            int s4 = __shfl(s, min(j + 4, jm));
            int s5 = __shfl(s, min(j + 5, jm));
            int s6 = __shfl(s, min(j + 6, jm));
            int s7 = __shfl(s, min(j + 7, jm));
            float v0 = B[(size_t)s0 * 64 + lane];
            float v1 = B[(size_t)s1 * 64 + lane];
            float v2 = B[(size_t)s2 * 64 + lane];
            float v3 = B[(size_t)s3 * 64 + lane];
            float v4 = B[(size_t)s4 * 64 + lane];
            float v5 = B[(size_t)s5 * 64 + lane];
            float v6 = B[(size_t)s6 * 64 + lane];
            float v7 = B[(size_t)s7 * 64 + lane];
            a0 += v0;
            a1 += (j + 1 < c) ? v1 : 0.f;
            a2 += (j + 2 < c) ? v2 : 0.f;
            a3 += (j + 3 < c) ? v3 : 0.f;
            a4 += (j + 4 < c) ? v4 : 0.f;
            a5 += (j + 5 < c) ? v5 : 0.f;
            a6 += (j + 6 < c) ? v6 : 0.f;
            a7 += (j + 7 < c) ? v7 : 0.f;
        }
    }
    float acc = ((a0 + a1) + (a2 + a3)) + ((a4 + a5) + (a6 + a7));
    Y[(size_t)wid * 64 + lane] = dinv[wid] * acc;
}

// transform 8->64: B2 = relu(y1@W1 + b1) * dinv
__global__ __launch_bounds__(256) void k_transform1n(
        const float* __restrict__ Y1, const float* __restrict__ W,
        const float* __restrict__ b, const float* __restrict__ dinv,
        float* __restrict__ Bout) {
    int wid = (blockIdx.x * 256 + threadIdx.x) >> 6;
    int lane = threadIdx.x & 63;
    if (wid >= N_NODES) return;
    const float4* yr = (const float4*)(Y1 + (size_t)wid * 8);
    float4 y0 = yr[0], y1 = yr[1];
    float acc = b[lane];
    acc += y0.x * W[0 * 64 + lane] + y0.y * W[1 * 64 + lane]
         + y0.z * W[2 * 64 + lane] + y0.w * W[3 * 64 + lane];
    acc += y1.x * W[4 * 64 + lane] + y1.y * W[5 * 64 + lane]
         + y1.z * W[6 * 64 + lane] + y1.w * W[7 * 64 + lane];
    Bout[(size_t)wid * 64 + lane] = fmaxf(acc, 0.f) * dinv[wid];
}

// transform 64->64: Bout = act(A@W + b) [* dinv]
template <int RELU, int SCALE>
__global__ __launch_bounds__(256) void k_transform64f(
        const float* __restrict__ A, const float* __restrict__ W,
        const float* __restrict__ b, const float* __restrict__ dinv,
        float* __restrict__ Bout) {
    __shared__ float Wl[64 * 64];
    for (int j = threadIdx.x; j < 64 * 64; j += 256) Wl[j] = W[j];
    __syncthreads();
    int wid = (blockIdx.x * 256 + threadIdx.x) >> 6;
    int lane = threadIdx.x & 63;
    if (wid >= N_NODES) return;
    const float* ar = A + (size_t)wid * 64;
    float acc = b[lane];
#pragma unroll
    for (int k = 0; k < 64; ++k) acc += ar[k] * Wl[k * 64 + lane];
    if (RELU) acc = fmaxf(acc, 0.f);
    if (SCALE) acc *= dinv[wid];
    Bout[(size_t)wid * 64 + lane] = acc;
}

// ---------------- pooling + heads ----------------

__global__ void k_gstart(const int* __restrict__ batch, int* __restrict__ gstart) {
    int g = threadIdx.x;
    int lo = 0, hi = N_NODES;
    while (lo < hi) {
        int mid = (lo + hi) >> 1;
        if (batch[mid] < g) lo = mid + 1; else hi = mid;
    }
    gstart[g] = lo;
    if (g == 0) gstart[N_GRAPHS] = N_NODES;
}

__global__ __launch_bounds__(256) void k_pool(
        const float* __restrict__ A, const int* __restrict__ gstart,
        float* __restrict__ xgp) {
    int g = blockIdx.x;
    int beg = gstart[g], end = gstart[g + 1];
    int lane = threadIdx.x & 63, grp = threadIdx.x >> 6;
    float acc = 0.f;
    for (int r = beg + grp; r < end; r += 4) acc += A[(size_t)r * 64 + lane];
    __shared__ float l[256];
    l[threadIdx.x] = acc;
    __syncthreads();
    if (threadIdx.x < 64) {
        float s = l[threadIdx.x] + l[threadIdx.x + 64] + l[threadIdx.x + 128] + l[threadIdx.x + 192];
        float c = (float)(end - beg);
        xgp[g * 64 + threadIdx.x] = s / fmaxf(c, 1.f);
    }
}

__global__ __launch_bounds__(256) void k_xglobal(
        const float* __restrict__ xgp, const float* __restrict__ Wg,
        const float* __restrict__ bg, float* __restrict__ xg) {
    int wid = (blockIdx.x * 256 + threadIdx.x) >> 6;
    int lane = threadIdx.x & 63;
    if (wid >= N_GRAPHS) return;
    float acc = bg[lane];
#pragma unroll 16
    for (int k = 0; k < 64; ++k) acc += xgp[wid * 64 + k] * Wg[k * 64 + lane];
    xg[wid * 64 + lane] = fmaxf(acc, 0.f);
}

__global__ void k_heuristic(const float* __restrict__ xg,
                            const float* __restrict__ Wh1, const float* __restrict__ bh1,
                            const float* __restrict__ Wh2, const float* __restrict__ bh2,
                            float* __restrict__ out) {
    int g = threadIdx.x;
    const float* r = xg + g * 64;
    float acc = bh2[0];
    for (int j = 0; j < 32; ++j) {
        float hj = bh1[j];
#pragma unroll 16
        for (int k = 0; k < 64; ++k) hj += r[k] * Wh1[k * 32 + j];
        acc += fmaxf(hj, 0.f) * Wh2[j];
    }
    out[g] = acc;
}

// node heads, stage 1: M = relu(h@Wm1+bm1) -> global; priority head fully in-register
__global__ __launch_bounds__(256) void k_mlp1(
        const float* __restrict__ h,
        const float* __restrict__ Wm1, const float* __restrict__ bm1,
        const float* __restrict__ Wp1, const float* __restrict__ bp1,
        const float* __restrict__ Wp2, const float* __restrict__ bp2,
        float* __restrict__ M, float* __restrict__ out_p) {
    __shared__ float Wm[64 * 64];   // [k][f]
    __shared__ float Wp[64 * 32];   // [k][j]
    for (int i = threadIdx.x; i < 64 * 64; i += 256) Wm[i] = Wm1[i];
    for (int i = threadIdx.x; i < 64 * 32; i += 256) Wp[i] = Wp1[i];
    __syncthreads();
    int wid = (blockIdx.x * 256 + threadIdx.x) >> 6;
    int lane = threadIdx.x & 63;
    if (wid >= N_NODES) return;
    const float* hr = h + (size_t)wid * 64;

    float m = bm1[lane];
#pragma unroll 16
    for (int k = 0; k < 64; ++k) m += hr[k] * Wm[k * 64 + lane];
    M[(size_t)wid * 64 + lane] = fmaxf(m, 0.f);

    int j = lane & 31;
    int kbase = (lane >> 5) * 32;
    float p = 0.f;
#pragma unroll 16
    for (int kk = 0; kk < 32; ++kk) {
        int k = kbase + kk;
        p += hr[k] * Wp[k * 32 + j];
    }
    p += __shfl_xor(p, 32);
    float q = fmaxf(p + bp1[j], 0.f) * Wp2[j];
#pragma unroll
    for (int off = 16; off; off >>= 1) q += __shfl_xor(q, off);
    if (lane == 0) out_p[wid] = q + bp2[0];
}

// node heads, stage 2: out_m[n][j] = M[n] . Wm2[:,j] + bm2[j] (thread per output)
__global__ __launch_bounds__(256) void k_mlp2(
        const float* __restrict__ M,
        const float* __restrict__ Wm2, const float* __restrict__ bm2,
        float* __restrict__ out_m) {
    __shared__ float W[64 * 9];
    __shared__ float bb[9];
    for (int i = threadIdx.x; i < 64 * 9; i += 256) W[i] = Wm2[i];
    if (threadIdx.x < 9) bb[threadIdx.x] = bm2[threadIdx.x];
    __syncthreads();
    int tid = blockIdx.x * 256 + threadIdx.x;
    if (tid >= N_NODES * 9) return;
    int n = tid / 9;
    int j = tid - n * 9;
    const float* Mr = M + (size_t)n * 64;
    float acc = bb[j];
#pragma unroll 16
    for (int k = 0; k < 64; ++k) acc += Mr[k] * W[k * 9 + j];
    out_m[tid] = acc;
}

// ---------------- launch ----------------

extern "C" void kernel_launch(void* const* d_in, const int* in_sizes, int n_in,
                              void* d_out, int out_size, void* d_ws, size_t ws_size,
                              hipStream_t stream) {
    const float* x    = (const float*)d_in[0];
    const int*   ei   = (const int*)d_in[1];
    const int*   batch= (const int*)d_in[2];
    const float* W1   = (const float*)d_in[3];
    const float* b1   = (const float*)d_in[4];
    const float* W2   = (const float*)d_in[5];
    const float* b2   = (const float*)d_in[6];
    const float* W3   = (const float*)d_in[7];
    const float* b3   = (const float*)d_in[8];
    const float* Wg   = (const float*)d_in[9];
    const float* bg   = (const float*)d_in[10];
    const float* Wh1  = (const float*)d_in[11];
    const float* bh1  = (const float*)d_in[12];
    const float* Wh2  = (const float*)d_in[13];
    const float* bh2  = (const float*)d_in[14];
    const float* Wm1  = (const float*)d_in[15];
    const float* bm1  = (const float*)d_in[16];
    const float* Wm2  = (const float*)d_in[17];
    const float* bm2  = (const float*)d_in[18];
    const float* Wp1  = (const float*)d_in[19];
    const float* bp1  = (const float*)d_in[20];
    const float* Wp2  = (const float*)d_in[21];
    const float* bp2  = (const float*)d_in[22];

    const int* e_src = ei;
    const int* e_dst = ei + N_EDGES;

    char* ws = (char*)d_ws;
    size_t off = 0;
    auto alloc = [&](size_t bytes) {
        void* p = ws + off;
        off += (bytes + 255) & ~(size_t)255;
        return p;
    };
    float* bufA   = (float*)alloc(N_NODES * 64 * sizeof(float));   // 25.6 MB
    float* bufB   = (float*)alloc(N_NODES * 64 * sizeof(float));   // 25.6 MB
    float* dinv   = (float*)alloc(N_NODES * sizeof(float));
    int*   rowp   = (int*)  alloc((N_NODES + 1) * sizeof(int));
    int*   esrc   = (int*)  alloc(N_EDGES * sizeof(int));          // 12.8 MB
    int*   hist   = (int*)  alloc((size_t)NBUCK * NPBLK * sizeof(int)); // 1.22 MB
    int*   btotal = (int*)  alloc(NBUCK * sizeof(int));
    int*   bbase  = (int*)  alloc(NBUCK * sizeof(int));
    int*   gstart = (int*)  alloc((N_GRAPHS + 1) * sizeof(int));
    float* xgp    = (float*)alloc(N_GRAPHS * 64 * sizeof(float));
    float* xg     = (float*)alloc(N_GRAPHS * 64 * sizeof(float));
    // aliases inside bufA (6.4M floats):
    //   pairs: [0, 3.2M) uints — live only during CSR build
    //   xs:    [4.0M, 4.8M) — live prescale..agg8
    //   y1:    [4.8M, 5.6M) — live agg8..transform1n
    // all dead before k_agg64 writes bufA in full.
    unsigned* pairs = (unsigned*)bufA;
    float* xs = bufA + 4000000;
    float* y1 = bufA + 4800000;
    float* M  = bufA;   // move-head hidden, reuses bufA at the end
    (void)ws_size; (void)n_in; (void)in_sizes; (void)out_size;

    float* out_h = (float*)d_out;                // [256]
    float* out_m = (float*)d_out + 256;          // [100000*9]
    float* out_p = (float*)d_out + 256 + 900000; // [100000]

    const int TB = 256;
    dim3 blkWave((N_NODES * 64 + TB - 1) / TB);  // one wave per node

    // CSR build — atomic-free 3-pass partition + per-bucket LDS sort
    k_hist<<<NPBLK, TB, 0, stream>>>(e_dst, hist);
    k_scan_rows<<<NBUCK, 512, 0, stream>>>(hist, btotal);
    k_scan_base<<<1, 1024, 0, stream>>>(btotal, bbase, rowp + N_NODES);
    k_scatter<<<NPBLK, TB, 0, stream>>>(e_src, e_dst, hist, bbase, pairs);
    k_sort<<<NBUCK, TB, 0, stream>>>(pairs, btotal, bbase, esrc, rowp, dinv);

    // layer 1 (aggregate in 8-dim input space, then transform)
    k_prescale<<<(N_NODES * 8 + TB - 1) / TB, TB, 0, stream>>>(x, dinv, xs);
    k_agg8<<<blkWave, TB, 0, stream>>>(xs, y1, dinv, rowp, esrc);
    k_transform1n<<<blkWave, TB, 0, stream>>>(y1, W1, b1, dinv, bufB);
    // layer 2
    k_agg64<<<blkWave, TB, 0, stream>>>(bufB, bufA, dinv, rowp, esrc);
    k_transform64f<1, 1><<<blkWave, TB, 0, stream>>>(bufA, W2, b2, dinv, bufB);
    // layer 3
    k_agg64<<<blkWave, TB, 0, stream>>>(bufB, bufA, dinv, rowp, esrc);
    k_transform64f<0, 0><<<blkWave, TB, 0, stream>>>(bufA, W3, b3, dinv, bufB); // h

    // pooling + global head (h = bufB)
    k_gstart<<<1, N_GRAPHS, 0, stream>>>(batch, gstart);
    k_pool<<<N_GRAPHS, TB, 0, stream>>>(bufB, gstart, xgp);
    k_xglobal<<<(N_GRAPHS * 64 + TB - 1) / TB, TB, 0, stream>>>(xgp, Wg, bg, xg);
    k_heuristic<<<1, N_GRAPHS, 0, stream>>>(xg, Wh1, bh1, Wh2, bh2, out_h);

    // node heads (two-stage, reduce-free)
    k_mlp1<<<blkWave, TB, 0, stream>>>(bufB, Wm1, bm1, Wp1, bp1, Wp2, bp2, M, out_p);
    k_mlp2<<<(N_NODES * 9 + TB - 1) / TB, TB, 0, stream>>>(M, Wm2, bm2, out_m);
}

// Round 7
// 524.822 us; speedup vs baseline: 3.4244x; 1.3232x over previous
//
#include <hip/hip_runtime.h>

#define N_NODES 100000
#define N_EDGES 3200000
#define N_GRAPHS 256
#define HID 64

// atomic-free bucketed CSR build
#define BSHIFT 7                 // 128 nodes per bucket
#define NPB 128                  // nodes per bucket
#define NBUCK 782                // ceil(100000/128)
#define PCHUNK 8192              // edges per partition block
#define NPBLK 391                // ceil(3200000/8192)
#define SCAP 5120                // per-bucket sort capacity (mean 4093, sigma 64 -> +16 sigma)

// pass A: per-block private LDS histogram over buckets
__global__ __launch_bounds__(256) void k_hist(
        const int* __restrict__ dst, int* __restrict__ hist) {
    __shared__ int h[NBUCK];
    int t = threadIdx.x;
    for (int j = t; j < NBUCK; j += 256) h[j] = 0;
    __syncthreads();
    int base = blockIdx.x * PCHUNK;
    int end = min(base + PCHUNK, N_EDGES);
    for (int i = base + t; i < end; i += 256)
        atomicAdd(&h[dst[i] >> BSHIFT], 1);
    __syncthreads();
    for (int j = t; j < NBUCK; j += 256) hist[j * NPBLK + blockIdx.x] = h[j];
}

// pass B1: per-bucket exclusive scan over block counts (in place), emit totals
__global__ __launch_bounds__(512) void k_scan_rows(
        int* __restrict__ hist, int* __restrict__ btotal) {
    __shared__ int s[512];
    int b = blockIdx.x, t = threadIdx.x;
    int v = (t < NPBLK) ? hist[b * NPBLK + t] : 0;
    s[t] = v;
    __syncthreads();
    for (int off = 1; off < 512; off <<= 1) {
        int add = (t >= off) ? s[t - off] : 0;
        __syncthreads();
        s[t] += add;
        __syncthreads();
    }
    if (t < NPBLK) hist[b * NPBLK + t] = s[t] - v;  // exclusive within bucket
    if (t == 511) btotal[b] = s[511];
}

// pass B2: exclusive scan over NBUCK bucket totals (single block, 1024 threads)
__global__ __launch_bounds__(1024) void k_scan_base(
        const int* __restrict__ btotal, int* __restrict__ bbase,
        int* __restrict__ rowp_last) {
    __shared__ int s[1024];
    int t = threadIdx.x;
    int v = (t < NBUCK) ? btotal[t] : 0;
    s[t] = v;
    __syncthreads();
    for (int off = 1; off < 1024; off <<= 1) {
        int add = (t >= off) ? s[t - off] : 0;
        __syncthreads();
        s[t] += add;
        __syncthreads();
    }
    if (t < NBUCK) bbase[t] = s[t] - v;
    if (t == NBUCK - 1) rowp_last[0] = s[t];
}

// pass C: scatter packed pairs using exact per-(block,bucket) offsets (LDS cursors)
__global__ __launch_bounds__(256) void k_scatter(
        const int* __restrict__ src, const int* __restrict__ dst,
        const int* __restrict__ hist, const int* __restrict__ bbase,
        unsigned* __restrict__ pairs) {
    __shared__ int cur[NBUCK];
    int t = threadIdx.x;
    for (int j = t; j < NBUCK; j += 256)
        cur[j] = bbase[j] + hist[j * NPBLK + blockIdx.x];
    __syncthreads();
    int base = blockIdx.x * PCHUNK;
    int end = min(base + PCHUNK, N_EDGES);
    for (int i = base + t; i < end; i += 256) {
        int d = dst[i], s = src[i];
        int b = d >> BSHIFT;
        int pos = atomicAdd(&cur[b], 1);
        pairs[pos] = (unsigned)s | ((unsigned)(d & (NPB - 1)) << 24);
    }
}

// pass D: per-bucket LDS counting sort -> sorted esrc + rowp + dinv
__global__ __launch_bounds__(256) void k_sort(
        const unsigned* __restrict__ pairs, const int* __restrict__ btotal,
        const int* __restrict__ bbase, int* __restrict__ esrc,
        int* __restrict__ rowp, float* __restrict__ dinv) {
    __shared__ int lcnt[NPB];
    __shared__ int lscan[NPB];
    __shared__ int lcur[NPB];
    __shared__ int lout[SCAP];
    int b = blockIdx.x, t = threadIdx.x;
    int nb = min(btotal[b], SCAP);
    int base = bbase[b];
    if (t < NPB) lcnt[t] = 0;
    __syncthreads();
    for (int i = t; i < nb; i += 256) atomicAdd(&lcnt[pairs[base + i] >> 24], 1);
    __syncthreads();
    if (t < NPB) lscan[t] = lcnt[t];
    __syncthreads();
    for (int off = 1; off < NPB; off <<= 1) {
        int add = (t < NPB && t >= off) ? lscan[t - off] : 0;
        __syncthreads();
        if (t < NPB) lscan[t] += add;
        __syncthreads();
    }
    if (t < NPB) lcur[t] = lscan[t] - lcnt[t];
    __syncthreads();
    for (int i = t; i < nb; i += 256) {
        unsigned u = pairs[base + i];
        int p = atomicAdd(&lcur[u >> 24], 1);
        lout[p] = (int)(u & 0x00FFFFFFu);
    }
    __syncthreads();
    for (int i = t; i < nb; i += 256) esrc[base + i] = lout[i];
    int node = b * NPB + t;
    if (t < NPB && node < N_NODES) {
        rowp[node] = base + lscan[t] - lcnt[t];
        dinv[node] = rsqrtf((float)lcnt[t] + 1.0f);  // in-degree + self-loop
    }
}

// ---------------- weight folding ----------------
// h = y3@W3 + b3 feeds only linear ops before nonlinearity, so fold:
//   Wpack[64][96] = [W3@Wm1 | W3@Wp1],  bpack[96] = [b3@Wm1+bm1 | b3@Wp1+bp1]
//   Wcg[64][64]   = W3@Wg,              bcg[64]   = b3@Wg + bg
__global__ __launch_bounds__(256) void k_fold(
        const float* __restrict__ W3, const float* __restrict__ b3,
        const float* __restrict__ Wm1, const float* __restrict__ bm1,
        const float* __restrict__ Wp1, const float* __restrict__ bp1,
        const float* __restrict__ Wg, const float* __restrict__ bg,
        float* __restrict__ Wpack, float* __restrict__ bpack,
        float* __restrict__ Wcg, float* __restrict__ bcg) {
    int tid = blockIdx.x * 256 + threadIdx.x;
    if (tid < 6144) {                       // Wpack
        int k = tid / 96, c = tid % 96;
        float s = 0.f;
        if (c < 64) {
#pragma unroll 16
            for (int j = 0; j < 64; ++j) s += W3[k * 64 + j] * Wm1[j * 64 + c];
        } else {
            int cc = c - 64;
#pragma unroll 16
            for (int j = 0; j < 64; ++j) s += W3[k * 64 + j] * Wp1[j * 32 + cc];
        }
        Wpack[tid] = s;
    } else if (tid < 10240) {               // Wcg
        int t2 = tid - 6144;
        int k = t2 / 64, c = t2 % 64;
        float s = 0.f;
#pragma unroll 16
        for (int j = 0; j < 64; ++j) s += W3[k * 64 + j] * Wg[j * 64 + c];
        Wcg[t2] = s;
    } else if (tid < 10336) {               // bpack
        int c = tid - 10240;
        float s;
        if (c < 64) {
            s = bm1[c];
            for (int j = 0; j < 64; ++j) s += b3[j] * Wm1[j * 64 + c];
        } else {
            int cc = c - 64;
            s = bp1[cc];
            for (int j = 0; j < 64; ++j) s += b3[j] * Wp1[j * 32 + cc];
        }
        bpack[c] = s;
    } else if (tid < 10400) {               // bcg
        int c = tid - 10336;
        float s = bg[c];
        for (int j = 0; j < 64; ++j) s += b3[j] * Wg[j * 64 + c];
        bcg[c] = s;
    }
}

// ---------------- GCN layers ----------------
// Re-associated pipeline:  xs = x*dinv;  y1 = agg(xs);  B2 = relu(y1@W1+b1)*dinv;
// y2 = agg(B2);  B3 = relu(y2@W2+b2)*dinv;  y3 = agg(B3);
// heads consume y3 directly via folded weights.

// prescale x (8 features) by dinv
__global__ __launch_bounds__(256) void k_prescale(
        const float* __restrict__ x, const float* __restrict__ dinv,
        float* __restrict__ xs) {
    int tid = blockIdx.x * 256 + threadIdx.x;
    if (tid >= N_NODES * 8) return;
    xs[tid] = x[tid] * dinv[tid >> 3];
}

// 8-feature aggregate: lane-per-edge, float4x2 row loads, butterfly reduce.
__global__ __launch_bounds__(256) void k_agg8(
        const float* __restrict__ xs, float* __restrict__ Y,
        const float* __restrict__ dinv, const int* __restrict__ rp,
        const int* __restrict__ esrc) {
    int wid = (blockIdx.x * 256 + threadIdx.x) >> 6;
    int lane = threadIdx.x & 63;
    if (wid >= N_NODES) return;
    int beg = rp[wid], end = rp[wid + 1];
    float4 lo = {0.f, 0.f, 0.f, 0.f}, hi = {0.f, 0.f, 0.f, 0.f};
    for (int e = beg + lane; e < end; e += 64) {
        int s = esrc[e];
        const float4* r = (const float4*)(xs + (size_t)s * 8);
        float4 a = r[0], b = r[1];
        lo.x += a.x; lo.y += a.y; lo.z += a.z; lo.w += a.w;
        hi.x += b.x; hi.y += b.y; hi.z += b.z; hi.w += b.w;
    }
#pragma unroll
    for (int off = 32; off; off >>= 1) {
        lo.x += __shfl_xor(lo.x, off); lo.y += __shfl_xor(lo.y, off);
        lo.z += __shfl_xor(lo.z, off); lo.w += __shfl_xor(lo.w, off);
        hi.x += __shfl_xor(hi.x, off); hi.y += __shfl_xor(hi.y, off);
        hi.z += __shfl_xor(hi.z, off); hi.w += __shfl_xor(hi.w, off);
    }
    if (lane == 0) {
        const float4* r = (const float4*)(xs + (size_t)wid * 8);
        float4 a = r[0], b = r[1];
        float dv = dinv[wid];
        float* yo = Y + (size_t)wid * 8;
        yo[0] = dv * (lo.x + a.x); yo[1] = dv * (lo.y + a.y);
        yo[2] = dv * (lo.z + a.z); yo[3] = dv * (lo.w + a.w);
        yo[4] = dv * (hi.x + b.x); yo[5] = dv * (hi.y + b.y);
        yo[6] = dv * (hi.z + b.z); yo[7] = dv * (hi.w + b.w);
    }
}

// 64-feature aggregate: 8-wide MLP batches, clamped-index tail with masked adds
__global__ __launch_bounds__(256) void k_agg64(
        const float* __restrict__ B, float* __restrict__ Y,
        const float* __restrict__ dinv, const int* __restrict__ rp,
        const int* __restrict__ esrc) {
    int wid = (blockIdx.x * 256 + threadIdx.x) >> 6;
    int lane = threadIdx.x & 63;
    if (wid >= N_NODES) return;
    int beg = rp[wid], end = rp[wid + 1];
    float a0 = B[(size_t)wid * 64 + lane];  // self loop
    float a1 = 0.f, a2 = 0.f, a3 = 0.f, a4 = 0.f, a5 = 0.f, a6 = 0.f, a7 = 0.f;
    for (int e0 = beg; e0 < end; e0 += 64) {
        int myE = e0 + lane;
        int s = (myE < end) ? esrc[myE] : 0;
        int c = min(64, end - e0);
        int jm = c - 1;
        for (int j = 0; j < c; j += 8) {
            int s0 = __shfl(s, j);
            int s1 = __shfl(s, min(j + 1, jm));
            int s2 = __shfl(s, min(j + 2, jm));
            int s3 = __shfl(s, min(j + 3, jm));
            int s4 = __shfl(s, min(j + 4, jm));
            int s5 = __shfl(s, min(j + 5, jm));
            int s6 = __shfl(s, min(j + 6, jm));
            int s7 = __shfl(s, min(j + 7, jm));
            float v0 = B[(size_t)s0 * 64 + lane];
            float v1 = B[(size_t)s1 * 64 + lane];
            float v2 = B[(size_t)s2 * 64 + lane];
            float v3 = B[(size_t)s3 * 64 + lane];
            float v4 = B[(size_t)s4 * 64 + lane];
            float v5 = B[(size_t)s5 * 64 + lane];
            float v6 = B[(size_t)s6 * 64 + lane];
            float v7 = B[(size_t)s7 * 64 + lane];
            a0 += v0;
            a1 += (j + 1 < c) ? v1 : 0.f;
            a2 += (j + 2 < c) ? v2 : 0.f;
            a3 += (j + 3 < c) ? v3 : 0.f;
            a4 += (j + 4 < c) ? v4 : 0.f;
            a5 += (j + 5 < c) ? v5 : 0.f;
            a6 += (j + 6 < c) ? v6 : 0.f;
            a7 += (j + 7 < c) ? v7 : 0.f;
        }
    }
    float acc = ((a0 + a1) + (a2 + a3)) + ((a4 + a5) + (a6 + a7));
    Y[(size_t)wid * 64 + lane] = dinv[wid] * acc;
}

// transform 8->64: B2 = relu(y1@W1 + b1) * dinv
__global__ __launch_bounds__(256) void k_transform1n(
        const float* __restrict__ Y1, const float* __restrict__ W,
        const float* __restrict__ b, const float* __restrict__ dinv,
        float* __restrict__ Bout) {
    int wid = (blockIdx.x * 256 + threadIdx.x) >> 6;
    int lane = threadIdx.x & 63;
    if (wid >= N_NODES) return;
    const float4* yr = (const float4*)(Y1 + (size_t)wid * 8);
    float4 y0 = yr[0], y1 = yr[1];
    float acc = b[lane];
    acc += y0.x * W[0 * 64 + lane] + y0.y * W[1 * 64 + lane]
         + y0.z * W[2 * 64 + lane] + y0.w * W[3 * 64 + lane];
    acc += y1.x * W[4 * 64 + lane] + y1.y * W[5 * 64 + lane]
         + y1.z * W[6 * 64 + lane] + y1.w * W[7 * 64 + lane];
    Bout[(size_t)wid * 64 + lane] = fmaxf(acc, 0.f) * dinv[wid];
}

// register-tiled GEMM: out[128 x NCOL tile] = act(A[128x64] @ W[64xNCOL] + bias)
// thread computes 8 rows x 4 cols. NCOL=64: 256 thr; NCOL=96: 384 thr.
// PHEAD: cols 64..95 are P1; reduce P1@Wp2+bp2 -> out_p in-block (no extra pass).
template <int NCOL, int RELU, int SCALE, int PHEAD>
__global__ __launch_bounds__(NCOL * 4) void k_gemm(
        const float* __restrict__ A, const float* __restrict__ W,
        const float* __restrict__ bias, const float* __restrict__ dinv,
        float* __restrict__ out,
        const float* __restrict__ Wp2, const float* __restrict__ bp2,
        float* __restrict__ out_p) {
    __shared__ float Al[128 * 64];
    __shared__ float Wl[64 * NCOL];
    __shared__ float pbuf[128 * 8];
    const int NTHR = NCOL * 4;
    int tid = threadIdx.x;
    int base = blockIdx.x * 128;

    // stage A tile (zero-fill OOB rows)
    for (int idx = tid; idx < 128 * 16; idx += NTHR) {
        int r = idx >> 4, c4 = idx & 15;
        float4 v = {0.f, 0.f, 0.f, 0.f};
        if (base + r < N_NODES)
            v = *(const float4*)(A + (size_t)(base + r) * 64 + c4 * 4);
        *(float4*)(Al + r * 64 + c4 * 4) = v;
    }
    // stage W
    for (int idx = tid; idx < 64 * (NCOL / 4); idx += NTHR) {
        int r = idx / (NCOL / 4), c4 = idx % (NCOL / 4);
        *(float4*)(Wl + r * NCOL + c4 * 4) = *(const float4*)(W + r * NCOL + c4 * 4);
    }
    __syncthreads();

    int tc = tid % (NCOL / 4);
    int tr = tid / (NCOL / 4);   // 0..15

    float acc[8][4];
#pragma unroll
    for (int i = 0; i < 8; ++i)
#pragma unroll
        for (int c = 0; c < 4; ++c) acc[i][c] = 0.f;

    for (int kb = 0; kb < 16; ++kb) {
        float w0[4], w1[4], w2[4], w3[4];
        {
            const float* wp = Wl + (kb * 4) * NCOL + tc * 4;
            float4 a = *(const float4*)(wp);
            float4 b = *(const float4*)(wp + NCOL);
            float4 c = *(const float4*)(wp + 2 * NCOL);
            float4 d = *(const float4*)(wp + 3 * NCOL);
            w0[0] = a.x; w0[1] = a.y; w0[2] = a.z; w0[3] = a.w;
            w1[0] = b.x; w1[1] = b.y; w1[2] = b.z; w1[3] = b.w;
            w2[0] = c.x; w2[1] = c.y; w2[2] = c.z; w2[3] = c.w;
            w3[0] = d.x; w3[1] = d.y; w3[2] = d.z; w3[3] = d.w;
        }
#pragma unroll
        for (int i = 0; i < 8; ++i) {
            float4 af = *(const float4*)(Al + (tr * 8 + i) * 64 + kb * 4);
#pragma unroll
            for (int c = 0; c < 4; ++c)
                acc[i][c] += af.x * w0[c] + af.y * w1[c] + af.z * w2[c] + af.w * w3[c];
        }
    }

    // epilogue
    float4 bv = *(const float4*)(bias + tc * 4);
    float wp2l[4] = {0.f, 0.f, 0.f, 0.f};
    if (PHEAD && tc >= 16) {
        float4 wv = *(const float4*)(Wp2 + (tc - 16) * 4);
        wp2l[0] = wv.x; wp2l[1] = wv.y; wp2l[2] = wv.z; wp2l[3] = wv.w;
    }
#pragma unroll
    for (int i = 0; i < 8; ++i) {
        int lr = tr * 8 + i;
        int r = base + lr;
        bool ok = r < N_NODES;
        float o0 = acc[i][0] + bv.x, o1 = acc[i][1] + bv.y;
        float o2 = acc[i][2] + bv.z, o3 = acc[i][3] + bv.w;
        if (RELU) {
            o0 = fmaxf(o0, 0.f); o1 = fmaxf(o1, 0.f);
            o2 = fmaxf(o2, 0.f); o3 = fmaxf(o3, 0.f);
        }
        if (SCALE) {
            float dv = ok ? dinv[r] : 0.f;
            o0 *= dv; o1 *= dv; o2 *= dv; o3 *= dv;
        }
        if (PHEAD && tc >= 16) {
            pbuf[lr * 8 + (tc - 16)] =
                o0 * wp2l[0] + o1 * wp2l[1] + o2 * wp2l[2] + o3 * wp2l[3];
        } else if (ok) {
            float4 st = {o0, o1, o2, o3};
            *(float4*)(out + (size_t)r * 64 + tc * 4) = st;
        }
    }
    if (PHEAD) {
        __syncthreads();
        if (tid < 128) {
            int r = base + tid;
            if (r < N_NODES) {
                float s = 0.f;
#pragma unroll
                for (int j = 0; j < 8; ++j) s += pbuf[tid * 8 + j];
                out_p[r] = s + bp2[0];
            }
        }
    }
}

// ---------------- pooling + heads ----------------

__global__ void k_gstart(const int* __restrict__ batch, int* __restrict__ gstart) {
    int g = threadIdx.x;
    int lo = 0, hi = N_NODES;
    while (lo < hi) {
        int mid = (lo + hi) >> 1;
        if (batch[mid] < g) lo = mid + 1; else hi = mid;
    }
    gstart[g] = lo;
    if (g == 0) gstart[N_GRAPHS] = N_NODES;
}

__global__ __launch_bounds__(256) void k_pool(
        const float* __restrict__ A, const int* __restrict__ gstart,
        float* __restrict__ xgp) {
    int g = blockIdx.x;
    int beg = gstart[g], end = gstart[g + 1];
    int lane = threadIdx.x & 63, grp = threadIdx.x >> 6;
    float acc = 0.f;
    for (int r = beg + grp; r < end; r += 4) acc += A[(size_t)r * 64 + lane];
    __shared__ float l[256];
    l[threadIdx.x] = acc;
    __syncthreads();
    if (threadIdx.x < 64) {
        float s = l[threadIdx.x] + l[threadIdx.x + 64] + l[threadIdx.x + 128] + l[threadIdx.x + 192];
        float c = (float)(end - beg);
        xgp[g * 64 + threadIdx.x] = s / fmaxf(c, 1.f);
    }
}

__global__ __launch_bounds__(256) void k_xglobal(
        const float* __restrict__ xgp, const float* __restrict__ Wg,
        const float* __restrict__ bg, float* __restrict__ xg) {
    int wid = (blockIdx.x * 256 + threadIdx.x) >> 6;
    int lane = threadIdx.x & 63;
    if (wid >= N_GRAPHS) return;
    float acc = bg[lane];
#pragma unroll 16
    for (int k = 0; k < 64; ++k) acc += xgp[wid * 64 + k] * Wg[k * 64 + lane];
    xg[wid * 64 + lane] = fmaxf(acc, 0.f);
}

__global__ void k_heuristic(const float* __restrict__ xg,
                            const float* __restrict__ Wh1, const float* __restrict__ bh1,
                            const float* __restrict__ Wh2, const float* __restrict__ bh2,
                            float* __restrict__ out) {
    int g = threadIdx.x;
    const float* r = xg + g * 64;
    float acc = bh2[0];
    for (int j = 0; j < 32; ++j) {
        float hj = bh1[j];
#pragma unroll 16
        for (int k = 0; k < 64; ++k) hj += r[k] * Wh1[k * 32 + j];
        acc += fmaxf(hj, 0.f) * Wh2[j];
    }
    out[g] = acc;
}

// out_m[n][j] = M[n] . Wm2[:,j] + bm2[j] (thread per output)
__global__ __launch_bounds__(256) void k_mlp2(
        const float* __restrict__ M,
        const float* __restrict__ Wm2, const float* __restrict__ bm2,
        float* __restrict__ out_m) {
    __shared__ float W[64 * 9];
    __shared__ float bb[9];
    for (int i = threadIdx.x; i < 64 * 9; i += 256) W[i] = Wm2[i];
    if (threadIdx.x < 9) bb[threadIdx.x] = bm2[threadIdx.x];
    __syncthreads();
    int tid = blockIdx.x * 256 + threadIdx.x;
    if (tid >= N_NODES * 9) return;
    int n = tid / 9;
    int j = tid - n * 9;
    const float* Mr = M + (size_t)n * 64;
    float acc = bb[j];
#pragma unroll 16
    for (int k = 0; k < 64; ++k) acc += Mr[k] * W[k * 9 + j];
    out_m[tid] = acc;
}

// ---------------- launch ----------------

extern "C" void kernel_launch(void* const* d_in, const int* in_sizes, int n_in,
                              void* d_out, int out_size, void* d_ws, size_t ws_size,
                              hipStream_t stream) {
    const float* x    = (const float*)d_in[0];
    const int*   ei   = (const int*)d_in[1];
    const int*   batch= (const int*)d_in[2];
    const float* W1   = (const float*)d_in[3];
    const float* b1   = (const float*)d_in[4];
    const float* W2   = (const float*)d_in[5];
    const float* b2   = (const float*)d_in[6];
    const float* W3   = (const float*)d_in[7];
    const float* b3   = (const float*)d_in[8];
    const float* Wg   = (const float*)d_in[9];
    const float* bg   = (const float*)d_in[10];
    const float* Wh1  = (const float*)d_in[11];
    const float* bh1  = (const float*)d_in[12];
    const float* Wh2  = (const float*)d_in[13];
    const float* bh2  = (const float*)d_in[14];
    const float* Wm1  = (const float*)d_in[15];
    const float* bm1  = (const float*)d_in[16];
    const float* Wm2  = (const float*)d_in[17];
    const float* bm2  = (const float*)d_in[18];
    const float* Wp1  = (const float*)d_in[19];
    const float* bp1  = (const float*)d_in[20];
    const float* Wp2  = (const float*)d_in[21];
    const float* bp2  = (const float*)d_in[22];

    const int* e_src = ei;
    const int* e_dst = ei + N_EDGES;

    char* ws = (char*)d_ws;
    size_t off = 0;
    auto alloc = [&](size_t bytes) {
        void* p = ws + off;
        off += (bytes + 255) & ~(size_t)255;
        return p;
    };
    float* bufA   = (float*)alloc(N_NODES * 64 * sizeof(float));   // 25.6 MB
    float* bufB   = (float*)alloc(N_NODES * 64 * sizeof(float));   // 25.6 MB
    float* dinv   = (float*)alloc(N_NODES * sizeof(float));
    int*   rowp   = (int*)  alloc((N_NODES + 1) * sizeof(int));
    int*   esrc   = (int*)  alloc(N_EDGES * sizeof(int));          // 12.8 MB
    int*   hist   = (int*)  alloc((size_t)NBUCK * NPBLK * sizeof(int)); // 1.22 MB
    int*   btotal = (int*)  alloc(NBUCK * sizeof(int));
    int*   bbase  = (int*)  alloc(NBUCK * sizeof(int));
    int*   gstart = (int*)  alloc((N_GRAPHS + 1) * sizeof(int));
    float* xgp    = (float*)alloc(N_GRAPHS * 64 * sizeof(float));
    float* xg     = (float*)alloc(N_GRAPHS * 64 * sizeof(float));
    float* Wpack  = (float*)alloc(64 * 96 * sizeof(float));
    float* bpack  = (float*)alloc(96 * sizeof(float));
    float* Wcg    = (float*)alloc(64 * 64 * sizeof(float));
    float* bcg    = (float*)alloc(64 * sizeof(float));
    // aliases inside bufA (6.4M floats):
    //   pairs: [0, 3.2M) uints — live only during CSR build
    //   xs:    [4.0M, 4.8M) — live prescale..agg8
    //   y1:    [4.8M, 5.6M) — live agg8..transform1n
    unsigned* pairs = (unsigned*)bufA;
    float* xs = bufA + 4000000;
    float* y1 = bufA + 4800000;
    (void)ws_size; (void)n_in; (void)in_sizes; (void)out_size;

    float* out_h = (float*)d_out;                // [256]
    float* out_m = (float*)d_out + 256;          // [100000*9]
    float* out_p = (float*)d_out + 256 + 900000; // [100000]

    const int TB = 256;
    dim3 blkWave((N_NODES * 64 + TB - 1) / TB);  // one wave per node
    const int NT = 782;                           // ceil(100000/128) GEMM tiles

    // CSR build — atomic-free 3-pass partition + per-bucket LDS sort
    k_hist<<<NPBLK, TB, 0, stream>>>(e_dst, hist);
    k_scan_rows<<<NBUCK, 512, 0, stream>>>(hist, btotal);
    k_scan_base<<<1, 1024, 0, stream>>>(btotal, bbase, rowp + N_NODES);
    k_scatter<<<NPBLK, TB, 0, stream>>>(e_src, e_dst, hist, bbase, pairs);
    k_sort<<<NBUCK, TB, 0, stream>>>(pairs, btotal, bbase, esrc, rowp, dinv);

    // fold W3 into head/global weights (tiny)
    k_fold<<<41, TB, 0, stream>>>(W3, b3, Wm1, bm1, Wp1, bp1, Wg, bg,
                                  Wpack, bpack, Wcg, bcg);

    // layer 1 (aggregate in 8-dim input space, then transform)
    k_prescale<<<(N_NODES * 8 + TB - 1) / TB, TB, 0, stream>>>(x, dinv, xs);
    k_agg8<<<blkWave, TB, 0, stream>>>(xs, y1, dinv, rowp, esrc);
    k_transform1n<<<blkWave, TB, 0, stream>>>(y1, W1, b1, dinv, bufB);
    // layer 2
    k_agg64<<<blkWave, TB, 0, stream>>>(bufB, bufA, dinv, rowp, esrc);      // y2
    k_gemm<64, 1, 1, 0><<<NT, 256, 0, stream>>>(bufA, W2, b2, dinv, bufB,
                                                nullptr, nullptr, nullptr); // B3'
    // layer 3 aggregate only (transform folded into heads)
    k_agg64<<<blkWave, TB, 0, stream>>>(bufB, bufA, dinv, rowp, esrc);      // y3

    // heads: [M | P1] in one GEMM; out_p reduced in-block; M -> bufB
    k_gemm<96, 1, 0, 1><<<NT, 384, 0, stream>>>(bufA, Wpack, bpack, nullptr, bufB,
                                                Wp2, bp2, out_p);
    k_mlp2<<<(N_NODES * 9 + TB - 1) / TB, TB, 0, stream>>>(bufB, Wm2, bm2, out_m);

    // pooling + global head (on y3 = bufA, via folded Wcg/bcg)
    k_gstart<<<1, N_GRAPHS, 0, stream>>>(batch, gstart);
    k_pool<<<N_GRAPHS, TB, 0, stream>>>(bufA, gstart, xgp);
    k_xglobal<<<(N_GRAPHS * 64 + TB - 1) / TB, TB, 0, stream>>>(xgp, Wcg, bcg, xg);
    k_heuristic<<<1, N_GRAPHS, 0, stream>>>(xg, Wh1, bh1, Wh2, bh2, out_h);
}